// Round 15
// baseline (318.682 us; speedup 1.0000x reference)
//
#include <hip/hip_runtime.h>
#include <hip/hip_bf16.h>
#include <stdint.h>

#define NE 8
#define HID 1024
#define FFN 4096
#define TOK 8192
#define TPE (TOK / NE)   // 1024 tokens per expert

typedef __attribute__((ext_vector_type(8))) short    bf16x8;
typedef __attribute__((ext_vector_type(4))) float    f32x4;
typedef __attribute__((ext_vector_type(4))) unsigned short ushort4v;
typedef __attribute__((ext_vector_type(8))) unsigned short ushort8v;
typedef __attribute__((ext_vector_type(4))) unsigned int   u32x4;

// ---------- helpers ----------

__device__ __forceinline__ unsigned short f2bf(float f) {
    union { float f; unsigned u; } c; c.f = f;
    unsigned r = c.u + 0x7fffu + ((c.u >> 16) & 1u);   // RNE, inputs finite
    return (unsigned short)(r >> 16);
}

// HW packed f32x2 -> bf16x2 (RNE). No builtin on gfx950 -> inline asm (T12).
__device__ __forceinline__ unsigned int cvt_pk_bf16(float lo, float hi) {
    unsigned int r;
    asm("v_cvt_pk_bf16_f32 %0, %1, %2" : "=v"(r) : "v"(lo), "v"(hi));
    return r;
}

__device__ __forceinline__ float gelu_tanh(float x) {
    const float c0 = 0.7978845608028654f;  // sqrt(2/pi)
    const float c1 = 0.044715f;
    float u = c0 * (x + c1 * x * x * x);
    float t = 1.0f - 2.0f / (1.0f + __expf(2.0f * u));
    return 0.5f * x * (1.0f + t);
}

typedef const __attribute__((address_space(1))) void gbl_void_t;
typedef __attribute__((address_space(3))) void lds_void_t;

__device__ __forceinline__ void gload_lds16(const void* g, void* l) {
    __builtin_amdgcn_global_load_lds((gbl_void_t*)g, (lds_void_t*)l, 16, 0, 0);
}

// ---------- prep: transpose-convert w2 [E][F][H] f32 -> w2t [E][H][F] bf16 ----

__global__ void transpose_cvt(const float* __restrict__ in,
                              unsigned short* __restrict__ out) {
    __shared__ unsigned short tile[64][65];
    const int e  = blockIdx.z;
    const int f0 = blockIdx.x * 64;
    const int h0 = blockIdx.y * 64;
    const float*     src = in  + (size_t)e * FFN * HID;
    unsigned short*  dst = out + (size_t)e * HID * FFN;
    const int t  = threadIdx.x;
    const int tr = t >> 4;        // 0..15
    const int tc = (t & 15) * 4;  // 0..60
#pragma unroll
    for (int i = 0; i < 4; i++) {
        int f = i * 16 + tr;
        f32x4 v = *(const f32x4*)(src + (size_t)(f0 + f) * HID + h0 + tc);
#pragma unroll
        for (int j = 0; j < 4; j++) tile[f][tc + j] = f2bf(v[j]);
    }
    __syncthreads();
#pragma unroll
    for (int i = 0; i < 4; i++) {
        int h = i * 16 + tr;
        ushort4v o;
#pragma unroll
        for (int j = 0; j < 4; j++) o[j] = tile[tc + j][h];
        *(ushort4v*)(dst + (size_t)(h0 + h) * FFN + f0 + tc) = o;
    }
}

// ---------- GEMM1 fused-cvt: C=gelu(x@w1^T), f32 inputs, 8-phase R11 skeleton
// Identical to R14 except PACK uses v_cvt_pk_bf16_f32 (4 instr instead of
// ~32 VALU per 8-elem pack) — removes the staging-VALU displacement that
// held MfmaUtil at 14.9%.

template <int GX, int GY>
__global__ __launch_bounds__(512, 2)
void gemm8f(const float* __restrict__ Af,
            const float* __restrict__ Bf,
            unsigned short* __restrict__ Cout, int M, int N, int K) {
    constexpr int BM = 256, BN = 256, BK = 64;
    constexpr int NH = 2, NI = 4, S = 32;
    constexpr int ABYTES = BM * BK * 2;   // 32768
    constexpr int BBYTES = BN * BK * 2;   // 32768
    constexpr int BUF = ABYTES + BBYTES;
    constexpr int NWG = NE * GX * GY;

    __shared__ __align__(16) char lds[2 * BUF];

    const int lin = blockIdx.x;
    const int wid = (lin & 7) * (NWG >> 3) + (lin >> 3);
    const int e   = wid / (GX * GY);
    const int rem = wid % (GX * GY);
    const int m0  = (rem % GX) * BM;
    const int n0  = (rem / GX) * BN;

    const float* Ae = Af + (size_t)e * M * K;
    const float* Be = Bf + (size_t)e * N * K;

    const int tid  = threadIdx.x;
    const int lane = tid & 63;
    const int w    = tid >> 6;
    const int wr   = w >> 2, wc = w & 3;
    const int fr   = lane & 15, fq = lane >> 4;

    // ---- staging addressing ----
    const int rA  = tid >> 3;             // 0..63
    const int kb  = (tid & 7) * 16;       // bf16-byte offset in 128B row
    const int kbs = kb ^ ((rA & 7) << 4); // swizzled bf16-byte offset
    const int eoff = kbs >> 1;            // f32 element offset (0..63, mult of 8)
    const float* aFb = Ae + (size_t)(m0 + rA) * K + eoff;
    const int   fB   = (rA / S) * 2 * S + (rA % S);
    const float* bFb = Be + (size_t)(n0 + fB) * K + eoff;
    char* dA0 = lds + rA * 128 + kb;
    char* dA1 = dA0 + BUF;
    char* dB0 = lds + ABYTES + fB * 128 + kb;
    char* dB1 = dB0 + BUF;

    auto LD_A = [&](int au, int kt, f32x4 (&g)[4]) {
        const float* s = aFb + (size_t)kt * 64;
        g[0] = *(const f32x4*)(s + (size_t)(au * 64) * K);
        g[1] = *(const f32x4*)(s + (size_t)(au * 64) * K + 4);
        g[2] = *(const f32x4*)(s + (size_t)(au * 64 + 128) * K);
        g[3] = *(const f32x4*)(s + (size_t)(au * 64 + 128) * K + 4);
    };
    auto LD_B = [&](int bu, int kt, f32x4 (&g)[4]) {
        const float* s = bFb + (size_t)kt * 64;
        g[0] = *(const f32x4*)(s + (size_t)(bu * S) * K);
        g[1] = *(const f32x4*)(s + (size_t)(bu * S) * K + 4);
        g[2] = *(const f32x4*)(s + (size_t)(bu * S + 128) * K);
        g[3] = *(const f32x4*)(s + (size_t)(bu * S + 128) * K + 4);
    };
    auto PACK = [&](const f32x4& lo, const f32x4& hi) {
        u32x4 o;
        o[0] = cvt_pk_bf16(lo[0], lo[1]);
        o[1] = cvt_pk_bf16(lo[2], lo[3]);
        o[2] = cvt_pk_bf16(hi[0], hi[1]);
        o[3] = cvt_pk_bf16(hi[2], hi[3]);
        return o;
    };
    auto WR_A = [&](int au, char* d, f32x4 (&g)[4]) {
        *(u32x4*)(d + (au * 64) * 128)       = PACK(g[0], g[1]);
        *(u32x4*)(d + (au * 64 + 128) * 128) = PACK(g[2], g[3]);
    };
    auto WR_B = [&](int bu, char* d, f32x4 (&g)[4]) {
        *(u32x4*)(d + (bu * S) * 128)        = PACK(g[0], g[1]);
        *(u32x4*)(d + (bu * S + 128) * 128)  = PACK(g[2], g[3]);
    };

    // ---- LDS read bases (swizzled, identical to R11) ----
    const int kx0 = (fq * 16) ^ ((lane & 7) << 4);
    const char* paA = lds + (wr * 128 + fr) * 128;
    const char* paB = lds + ABYTES + (wc * (BN / 4) + fr) * 128;
    const char* pa0k0 = paA + kx0;        const char* pa0k1 = paA + (kx0 ^ 64);
    const char* pa1k0 = pa0k0 + BUF;      const char* pa1k1 = pa0k1 + BUF;
    const char* pb0k0 = paB + kx0;        const char* pb0k1 = paB + (kx0 ^ 64);
    const char* pb1k0 = pb0k0 + BUF;      const char* pb1k1 = pb0k1 + BUF;

    bf16x8 a[4][2], b0[NH][2], b1[NH][2];

    auto LDA = [&](const char* p0, const char* p1, int mq) {
#pragma unroll
        for (int mi = 0; mi < 4; mi++) {
            a[mi][0] = *(const bf16x8*)(p0 + mq * 8192 + mi * 2048);
            a[mi][1] = *(const bf16x8*)(p1 + mq * 8192 + mi * 2048);
        }
    };
    auto LDB = [&](const char* p0, const char* p1, int nq, bf16x8 (&bb)[NH][2]) {
#pragma unroll
        for (int ni = 0; ni < NH; ni++) {
            bb[ni][0] = *(const bf16x8*)(p0 + (nq * (BN / 8) + ni * 16) * 128);
            bb[ni][1] = *(const bf16x8*)(p1 + (nq * (BN / 8) + ni * 16) * 128);
        }
    };

    f32x4 acc[8][NI];

    auto MMQ = [&](int mq, int nq, bf16x8 (&bb)[NH][2]) {
        __builtin_amdgcn_s_setprio(1);
#pragma unroll
        for (int mi = 0; mi < 4; mi++)
#pragma unroll
            for (int ni = 0; ni < NH; ni++) {
                f32x4& c = acc[mq * 4 + mi][nq * NH + ni];
                c = __builtin_amdgcn_mfma_f32_16x16x32_bf16(a[mi][0], bb[ni][0], c, 0, 0, 0);
                c = __builtin_amdgcn_mfma_f32_16x16x32_bf16(a[mi][1], bb[ni][1], c, 0, 0, 0);
            }
        __builtin_amdgcn_s_setprio(0);
    };

#define MIDBAR()  __builtin_amdgcn_s_barrier();                                      \
                  asm volatile("s_waitcnt lgkmcnt(0)" ::: "memory")
#define ENDBAR()  __builtin_amdgcn_s_barrier()
#define LGHINT()  asm volatile("s_waitcnt lgkmcnt(8)" ::: "memory")

    const int NT   = K / BK;
    const int NTm1 = NT - 1;

    // prologue: straight-line stage T0 {A0,A1,B0,B1}, T1 {A0,B0,B1};
    // preload pipeline regs: gO = A1(T1) for ph1, gE = A0(T2) for ph2.
    f32x4 gO[4], gE[4];
    {
        f32x4 t0[4];
        LD_A(0, 0, t0); WR_A(0, dA0, t0);
        LD_A(1, 0, t0); WR_A(1, dA0, t0);
        LD_B(0, 0, t0); WR_B(0, dB0, t0);
        LD_B(1, 0, t0); WR_B(1, dB0, t0);
        LD_A(0, 1, t0); WR_A(0, dA1, t0);
        LD_B(0, 1, t0); WR_B(0, dB1, t0);
        LD_B(1, 1, t0); WR_B(1, dB1, t0);
    }
    LD_A(1, 1, gO);
    LD_A(0, (2 < NT ? 2 : NTm1), gE);
#pragma unroll
    for (int i = 0; i < 8; i++)
#pragma unroll
        for (int j = 0; j < NI; j++) acc[i][j] = f32x4{0.f, 0.f, 0.f, 0.f};
    asm volatile("s_waitcnt lgkmcnt(0)" ::: "memory");
    __builtin_amdgcn_s_barrier();

    const int NW = NT / 2;
    for (int ww = 0; ww < NW; ++ww) {
        const int T = 2 * ww;
        const int kt2 = (T + 2 < NT) ? T + 2 : NTm1;
        const int kt3 = (T + 3 < NT) ? T + 3 : NTm1;
        const int kt4 = (T + 4 < NT) ? T + 4 : NTm1;

        // ---- buf0 half: tile T ----
        LDA(pa0k0, pa0k1, 0); LDB(pb0k0, pb0k1, 0, b0); LGHINT();
        MIDBAR();
        WR_A(1, dA1, gO); LD_B(0, kt2, gO);          // ph1: write A1(T+1)
        MMQ(0, 0, b0); ENDBAR();
        LDB(pb0k0, pb0k1, 1, b1);
        MIDBAR();
        WR_A(0, dA0, gE); LD_B(1, kt2, gE);          // ph2: write A0(T+2)
        MMQ(0, 1, b1); ENDBAR();
        LDA(pa0k0, pa0k1, 1);
        MIDBAR();
        WR_B(0, dB0, gO); LD_A(1, kt2, gO);          // ph3: write B0(T+2)
        MMQ(1, 1, b1); ENDBAR();
        MIDBAR();
        WR_B(1, dB0, gE); LD_A(0, kt3, gE);          // ph4: write B1(T+2)
        MMQ(1, 0, b0); ENDBAR();
        // ---- buf1 half: tile T+1 ----
        LDA(pa1k0, pa1k1, 0); LDB(pb1k0, pb1k1, 0, b0); LGHINT();
        MIDBAR();
        WR_A(1, dA0, gO); LD_B(0, kt3, gO);          // ph5: write A1(T+2)
        MMQ(0, 0, b0); ENDBAR();
        LDB(pb1k0, pb1k1, 1, b1);
        MIDBAR();
        WR_A(0, dA1, gE); LD_B(1, kt3, gE);          // ph6: write A0(T+3)
        MMQ(0, 1, b1); ENDBAR();
        LDA(pa1k0, pa1k1, 1);
        MIDBAR();
        WR_B(0, dB1, gO); LD_A(1, kt3, gO);          // ph7: write B0(T+3)
        MMQ(1, 1, b1); ENDBAR();
        MIDBAR();
        WR_B(1, dB1, gE); LD_A(0, kt4, gE);          // ph8: write B1(T+3)
        MMQ(1, 0, b0); ENDBAR();
    }

    // epilogue: gelu -> bf16; C/D layout col = lane&15, row = (lane>>4)*4 + r
    const int r0 = m0 + wr * 128 + fq * 4;
    const int c0 = n0 + wc * (BN / 4) + fr;
    unsigned short* C = Cout + (size_t)e * M * N;
#pragma unroll
    for (int mi = 0; mi < 8; mi++)
#pragma unroll
        for (int ni = 0; ni < NI; ni++) {
            int row = r0 + mi * 16, col = c0 + ni * 16;
#pragma unroll
            for (int r = 0; r < 4; r++)
                C[(size_t)(row + r) * N + col] = f2bf(gelu_tanh(acc[mi][ni][r]));
        }
#undef MIDBAR
#undef ENDBAR
#undef LGHINT
}

// ---------- 8-phase GEMM-BT (R11, proven) for GEMM2 ------------------------

template <int BN, int GX, int GY, bool GELU>
__global__ __launch_bounds__(512, 2)
void gemm8p(const unsigned short* __restrict__ A,
            const unsigned short* __restrict__ B,
            void* __restrict__ Cout, int M, int N, int K) {
    constexpr int BM = 256, BK = 64;
    constexpr int NH = BN / 128;
    constexpr int NI = 2 * NH;
    constexpr int LB = BN / 128;
    constexpr int S  = BN / 8;
    constexpr int ABYTES = BM * BK * 2;
    constexpr int BBYTES = BN * BK * 2;
    constexpr int BUF = ABYTES + BBYTES;
    constexpr int VMC = 2 + 2 * LB;
    constexpr int NWG = NE * GX * GY;

    __shared__ __align__(16) char lds[2 * BUF];

    const int lin = blockIdx.x;
    const int wid = (lin & 7) * (NWG >> 3) + (lin >> 3);
    const int e   = wid / (GX * GY);
    const int rem = wid % (GX * GY);
    const int m0  = (rem % GX) * BM;
    const int n0  = (rem / GX) * BN;

    const size_t K2 = (size_t)K * 2;
    const char* Ae = (const char*)(A + (size_t)e * M * K);
    const char* Be = (const char*)(B + (size_t)e * N * K);

    const int tid  = threadIdx.x;
    const int lane = tid & 63;
    const int w    = tid >> 6;
    const int wr   = w >> 2, wc = w & 3;
    const int fr   = lane & 15, fq = lane >> 4;

    const int rA  = tid >> 3;
    const int kb  = (tid & 7) * 16;
    const int kbs = kb ^ ((rA & 7) << 4);
    const char* aptr = Ae + (size_t)(m0 + rA) * K2 + kbs;
    const int   fB   = (rA / S) * 2 * S + (rA % S);
    const char* bptr = Be + (size_t)(n0 + fB) * K2 + kbs;
    char* dA0 = lds + rA * 128 + kb;
    char* dA1 = dA0 + BUF;
    char* dB0 = lds + ABYTES + fB * 128 + kb;
    char* dB1 = dB0 + BUF;

    auto SA = [&](int au, int kt, char* d) {
        const char* s = aptr + (size_t)kt * 128;
#pragma unroll
        for (int i = 0; i < 2; i++)
            gload_lds16(s + (size_t)(au * 64 + i * 128) * K2,
                        d + (au * 64 + i * 128) * 128);
    };
    auto SB = [&](int bu, int kt, char* d) {
        const char* s = bptr + (size_t)kt * 128;
#pragma unroll
        for (int i = 0; i < LB; i++)
            gload_lds16(s + (size_t)(bu * S + i * 128) * K2,
                        d + (bu * S + i * 128) * 128);
    };

    const int kx0 = (fq * 16) ^ ((lane & 7) << 4);
    const char* paA = lds + (wr * 128 + fr) * 128;
    const char* paB = lds + ABYTES + (wc * (BN / 4) + fr) * 128;
    const char* pa0k0 = paA + kx0;        const char* pa0k1 = paA + (kx0 ^ 64);
    const char* pa1k0 = pa0k0 + BUF;      const char* pa1k1 = pa0k1 + BUF;
    const char* pb0k0 = paB + kx0;        const char* pb0k1 = paB + (kx0 ^ 64);
    const char* pb1k0 = pb0k0 + BUF;      const char* pb1k1 = pb0k1 + BUF;

    f32x4 acc[8][NI];
#pragma unroll
    for (int i = 0; i < 8; i++)
#pragma unroll
        for (int j = 0; j < NI; j++) acc[i][j] = f32x4{0.f, 0.f, 0.f, 0.f};

    bf16x8 a[4][2], b0[NH][2], b1[NH][2];

    auto LDA = [&](const char* p0, const char* p1, int mq) {
#pragma unroll
        for (int mi = 0; mi < 4; mi++) {
            a[mi][0] = *(const bf16x8*)(p0 + mq * 8192 + mi * 2048);
            a[mi][1] = *(const bf16x8*)(p1 + mq * 8192 + mi * 2048);
        }
    };
    auto LDB = [&](const char* p0, const char* p1, int nq, bf16x8 (&bb)[NH][2]) {
#pragma unroll
        for (int ni = 0; ni < NH; ni++) {
            bb[ni][0] = *(const bf16x8*)(p0 + (nq * (BN / 8) + ni * 16) * 128);
            bb[ni][1] = *(const bf16x8*)(p1 + (nq * (BN / 8) + ni * 16) * 128);
        }
    };
    auto MMQ = [&](int mq, int nq, bf16x8 (&bb)[NH][2]) {
        __builtin_amdgcn_s_setprio(1);
#pragma unroll
        for (int mi = 0; mi < 4; mi++)
#pragma unroll
            for (int ni = 0; ni < NH; ni++) {
                f32x4& c = acc[mq * 4 + mi][nq * NH + ni];
                c = __builtin_amdgcn_mfma_f32_16x16x32_bf16(a[mi][0], bb[ni][0], c, 0, 0, 0);
                c = __builtin_amdgcn_mfma_f32_16x16x32_bf16(a[mi][1], bb[ni][1], c, 0, 0, 0);
            }
        __builtin_amdgcn_s_setprio(0);
    };

#define MIDBAR()  __builtin_amdgcn_s_barrier();                                      \
                  asm volatile("s_waitcnt lgkmcnt(0)" ::: "memory")
#define ENDBAR()  __builtin_amdgcn_s_barrier()
#define LGHINT()  asm volatile("s_waitcnt lgkmcnt(8)" ::: "memory")
#define VMW()     asm volatile("s_waitcnt vmcnt(%0)" :: "n"(VMC) : "memory")

    const int NT   = K / BK;
    const int NTm1 = NT - 1;

    SA(0, 0, dA0); SB(0, 0, dB0); SB(1, 0, dB0); SA(1, 0, dA0);
    SA(0, 1, dA1); SB(0, 1, dB1); SB(1, 1, dB1);
    VMW();
    __builtin_amdgcn_s_barrier();

    const int NW = NT / 2;
    for (int ww = 0; ww < NW; ++ww) {
        const int T = 2 * ww;
        const int kt1 = T + 1;
        const int kt2 = (T + 2 < NT) ? T + 2 : NTm1;
        const int kt3 = (T + 3 < NT) ? T + 3 : NTm1;

        LDA(pa0k0, pa0k1, 0); LDB(pb0k0, pb0k1, 0, b0); SA(1, kt1, dA1); LGHINT();
        MIDBAR(); MMQ(0, 0, b0); ENDBAR();
        LDB(pb0k0, pb0k1, 1, b1); SA(0, kt2, dA0);
        MIDBAR(); MMQ(0, 1, b1); ENDBAR();
        LDA(pa0k0, pa0k1, 1); SB(0, kt2, dB0);
        MIDBAR(); MMQ(1, 1, b1); ENDBAR();
        SB(1, kt2, dB0);
        MIDBAR(); MMQ(1, 0, b0); VMW(); ENDBAR();
        LDA(pa1k0, pa1k1, 0); LDB(pb1k0, pb1k1, 0, b0); SA(1, kt2, dA0); LGHINT();
        MIDBAR(); MMQ(0, 0, b0); ENDBAR();
        LDB(pb1k0, pb1k1, 1, b1); SA(0, kt3, dA1);
        MIDBAR(); MMQ(0, 1, b1); ENDBAR();
        LDA(pa1k0, pa1k1, 1); SB(0, kt3, dB1);
        MIDBAR(); MMQ(1, 1, b1); ENDBAR();
        SB(1, kt3, dB1);
        MIDBAR(); MMQ(1, 0, b0); VMW(); ENDBAR();
    }
    asm volatile("s_waitcnt vmcnt(0)" ::: "memory");

    const int r0 = m0 + wr * 128 + fq * 4;
    const int c0 = n0 + wc * (BN / 4) + fr;
    if constexpr (GELU) {
        unsigned short* C = (unsigned short*)Cout + (size_t)e * M * N;
#pragma unroll
        for (int mi = 0; mi < 8; mi++)
#pragma unroll
            for (int ni = 0; ni < NI; ni++) {
                int row = r0 + mi * 16, col = c0 + ni * 16;
#pragma unroll
                for (int r = 0; r < 4; r++)
                    C[(size_t)(row + r) * N + col] = f2bf(gelu_tanh(acc[mi][ni][r]));
            }
    } else {
        float* C = (float*)Cout + (size_t)e * M * N;
#pragma unroll
        for (int mi = 0; mi < 8; mi++)
#pragma unroll
            for (int ni = 0; ni < NI; ni++) {
                int row = r0 + mi * 16, col = c0 + ni * 16;
#pragma unroll
                for (int r = 0; r < 4; r++)
                    C[(size_t)(row + r) * N + col] = acc[mi][ni][r];
            }
    }
#undef MIDBAR
#undef ENDBAR
#undef LGHINT
#undef VMW
}

// ---------- fallback: fused fp32, zero workspace (correctness insurance) ----------

__global__ void fused_fallback(const float* __restrict__ x,
                               const float* __restrict__ w1,
                               const float* __restrict__ w2,
                               float* __restrict__ out) {
    __shared__ float xs[HID];
    __shared__ float hs[FFN];
    const int tok = blockIdx.x;
    const int e   = tok / TPE;
    const float* w1e = w1 + (size_t)e * FFN * HID;
    const float* w2e = w2 + (size_t)e * FFN * HID;
    const int t = threadIdx.x;
    for (int i = t; i < HID; i += 256) xs[i] = x[(size_t)tok * HID + i];
    __syncthreads();
    for (int f = t; f < FFN; f += 256) {
        const float* wr_ = w1e + (size_t)f * HID;
        float s = 0.f;
        for (int k = 0; k < HID; k++) s += xs[k] * wr_[k];
        hs[f] = gelu_tanh(s);
    }
    __syncthreads();
    for (int h = t; h < HID; h += 256) {
        float s = 0.f;
        for (int f = 0; f < FFN; f++) s += hs[f] * w2e[(size_t)f * HID + h];
        out[(size_t)tok * HID + h] = s;
    }
}

// ---------- launch ----------

extern "C" void kernel_launch(void* const* d_in, const int* in_sizes, int n_in,
                              void* d_out, int out_size, void* d_ws, size_t ws_size,
                              hipStream_t stream) {
    const float* x  = (const float*)d_in[0];
    const float* w1 = (const float*)d_in[1];
    const float* w2 = (const float*)d_in[2];
    float* out = (float*)d_out;

    const size_t W2B = (size_t)NE * FFN * HID * 2;   // 64 MB  bf16 w2t
    const size_t HB  = (size_t)TOK * FFN * 2;        // 64 MB  bf16 h
    const size_t need = W2B + HB;                    // 128 MB

    if (ws_size >= need) {
        char* ws = (char*)d_ws;
        unsigned short* w2t = (unsigned short*)ws;
        unsigned short* hb  = (unsigned short*)(ws + W2B);

        // prep: only w2 transpose-convert (192 MB traffic)
        transpose_cvt<<<dim3(FFN / 64, HID / 64, NE), 256, 0, stream>>>(w2, w2t);

        // GEMM1 fused-cvt: h = gelu(x @ w1^T), f32 inputs -> 512 blocks
        gemm8f<TPE / 256, FFN / 256><<<NE * (TPE / 256) * (FFN / 256), 512, 0, stream>>>(
            x, w1, hb, TPE, FFN, HID);
        // GEMM2: out = h @ w2t^T -> 256 blocks (R11 proven 8-phase)
        gemm8p<128, TPE / 256, HID / 128, false><<<NE * (TPE / 256) * (HID / 128), 512, 0, stream>>>(
            hb, w2t, out, TPE, HID, FFN);
    } else {
        fused_fallback<<<TOK, 256, 0, stream>>>(x, w1, w2, out);
    }
}

// Round 16
// 293.423 us; speedup vs baseline: 1.0861x; 1.0861x over previous
//
#include <hip/hip_runtime.h>
#include <hip/hip_bf16.h>
#include <stdint.h>

#define NE 8
#define HID 1024
#define FFN 4096
#define TOK 8192
#define TPE (TOK / NE)   // 1024 tokens per expert

typedef __attribute__((ext_vector_type(8))) short    bf16x8;
typedef __attribute__((ext_vector_type(4))) float    f32x4;
typedef __attribute__((ext_vector_type(4))) unsigned short ushort4v;
typedef __attribute__((ext_vector_type(8))) unsigned short ushort8v;
typedef __attribute__((ext_vector_type(4))) unsigned int   u32x4;

// ---------- helpers ----------

__device__ __forceinline__ unsigned short f2bf(float f) {
    union { float f; unsigned u; } c; c.f = f;
    unsigned r = c.u + 0x7fffu + ((c.u >> 16) & 1u);   // RNE, inputs finite
    return (unsigned short)(r >> 16);
}

// Compiler-visible packed f32x2 -> bf16x2 (RNE). NOT inline asm (m240 lesson:
// hand-written cvt_pk asm spills; the intrinsic schedules fine).
__device__ __forceinline__ unsigned int pk2(float lo, float hi) {
    float2 f2; f2.x = lo; f2.y = hi;
    __hip_bfloat162 b = __float22bfloat162_rn(f2);
    union { __hip_bfloat162 b; unsigned int u; } c; c.b = b;
    return c.u;
}

__device__ __forceinline__ float gelu_tanh(float x) {
    const float c0 = 0.7978845608028654f;  // sqrt(2/pi)
    const float c1 = 0.044715f;
    float u = c0 * (x + c1 * x * x * x);
    float t = 1.0f - 2.0f / (1.0f + __expf(2.0f * u));
    return 0.5f * x * (1.0f + t);
}

typedef const __attribute__((address_space(1))) void gbl_void_t;
typedef __attribute__((address_space(3))) void lds_void_t;

__device__ __forceinline__ void gload_lds16(const void* g, void* l) {
    __builtin_amdgcn_global_load_lds((gbl_void_t*)g, (lds_void_t*)l, 16, 0, 0);
}

// ---------- prep: transpose-convert w2 [E][F][H] f32 -> w2t [E][H][F] bf16 ----

__global__ void transpose_cvt(const float* __restrict__ in,
                              unsigned short* __restrict__ out) {
    __shared__ unsigned short tile[64][65];
    const int e  = blockIdx.z;
    const int f0 = blockIdx.x * 64;
    const int h0 = blockIdx.y * 64;
    const float*     src = in  + (size_t)e * FFN * HID;
    unsigned short*  dst = out + (size_t)e * HID * FFN;
    const int t  = threadIdx.x;
    const int tr = t >> 4;        // 0..15
    const int tc = (t & 15) * 4;  // 0..60
#pragma unroll
    for (int i = 0; i < 4; i++) {
        int f = i * 16 + tr;
        f32x4 v = *(const f32x4*)(src + (size_t)(f0 + f) * HID + h0 + tc);
#pragma unroll
        for (int j = 0; j < 4; j++) tile[f][tc + j] = f2bf(v[j]);
    }
    __syncthreads();
#pragma unroll
    for (int i = 0; i < 4; i++) {
        int h = i * 16 + tr;
        ushort4v o;
#pragma unroll
        for (int j = 0; j < 4; j++) o[j] = tile[tc + j][h];
        *(ushort4v*)(dst + (size_t)(h0 + h) * FFN + f0 + tc) = o;
    }
}

// ---------- GEMM1 fused-cvt: C=gelu(x@w1^T), f32 inputs, 8-phase R11 skeleton
// R14 skeleton verbatim; PACK via __float22bfloat162_rn (compiler intrinsic,
// lowers to v_cvt_pk_bf16_f32 without the R15 asm-induced spills).

template <int GX, int GY>
__global__ __launch_bounds__(512, 2)
void gemm8f(const float* __restrict__ Af,
            const float* __restrict__ Bf,
            unsigned short* __restrict__ Cout, int M, int N, int K) {
    constexpr int BM = 256, BN = 256, BK = 64;
    constexpr int NH = 2, NI = 4, S = 32;
    constexpr int ABYTES = BM * BK * 2;   // 32768
    constexpr int BBYTES = BN * BK * 2;   // 32768
    constexpr int BUF = ABYTES + BBYTES;
    constexpr int NWG = NE * GX * GY;

    __shared__ __align__(16) char lds[2 * BUF];

    const int lin = blockIdx.x;
    const int wid = (lin & 7) * (NWG >> 3) + (lin >> 3);
    const int e   = wid / (GX * GY);
    const int rem = wid % (GX * GY);
    const int m0  = (rem % GX) * BM;
    const int n0  = (rem / GX) * BN;

    const float* Ae = Af + (size_t)e * M * K;
    const float* Be = Bf + (size_t)e * N * K;

    const int tid  = threadIdx.x;
    const int lane = tid & 63;
    const int w    = tid >> 6;
    const int wr   = w >> 2, wc = w & 3;
    const int fr   = lane & 15, fq = lane >> 4;

    // ---- staging addressing ----
    const int rA  = tid >> 3;             // 0..63
    const int kb  = (tid & 7) * 16;       // bf16-byte offset in 128B row
    const int kbs = kb ^ ((rA & 7) << 4); // swizzled bf16-byte offset
    const int eoff = kbs >> 1;            // f32 element offset (0..63, mult of 8)
    const float* aFb = Ae + (size_t)(m0 + rA) * K + eoff;
    const int   fB   = (rA / S) * 2 * S + (rA % S);
    const float* bFb = Be + (size_t)(n0 + fB) * K + eoff;
    char* dA0 = lds + rA * 128 + kb;
    char* dA1 = dA0 + BUF;
    char* dB0 = lds + ABYTES + fB * 128 + kb;
    char* dB1 = dB0 + BUF;

    auto LD_A = [&](int au, int kt, f32x4 (&g)[4]) {
        const float* s = aFb + (size_t)kt * 64;
        g[0] = *(const f32x4*)(s + (size_t)(au * 64) * K);
        g[1] = *(const f32x4*)(s + (size_t)(au * 64) * K + 4);
        g[2] = *(const f32x4*)(s + (size_t)(au * 64 + 128) * K);
        g[3] = *(const f32x4*)(s + (size_t)(au * 64 + 128) * K + 4);
    };
    auto LD_B = [&](int bu, int kt, f32x4 (&g)[4]) {
        const float* s = bFb + (size_t)kt * 64;
        g[0] = *(const f32x4*)(s + (size_t)(bu * S) * K);
        g[1] = *(const f32x4*)(s + (size_t)(bu * S) * K + 4);
        g[2] = *(const f32x4*)(s + (size_t)(bu * S + 128) * K);
        g[3] = *(const f32x4*)(s + (size_t)(bu * S + 128) * K + 4);
    };
    auto PACK = [&](const f32x4& lo, const f32x4& hi) {
        u32x4 o;
        o[0] = pk2(lo[0], lo[1]);
        o[1] = pk2(lo[2], lo[3]);
        o[2] = pk2(hi[0], hi[1]);
        o[3] = pk2(hi[2], hi[3]);
        return o;
    };
    auto WR_A = [&](int au, char* d, f32x4 (&g)[4]) {
        *(u32x4*)(d + (au * 64) * 128)       = PACK(g[0], g[1]);
        *(u32x4*)(d + (au * 64 + 128) * 128) = PACK(g[2], g[3]);
    };
    auto WR_B = [&](int bu, char* d, f32x4 (&g)[4]) {
        *(u32x4*)(d + (bu * S) * 128)        = PACK(g[0], g[1]);
        *(u32x4*)(d + (bu * S + 128) * 128)  = PACK(g[2], g[3]);
    };

    // ---- LDS read bases (swizzled, identical to R11) ----
    const int kx0 = (fq * 16) ^ ((lane & 7) << 4);
    const char* paA = lds + (wr * 128 + fr) * 128;
    const char* paB = lds + ABYTES + (wc * (BN / 4) + fr) * 128;
    const char* pa0k0 = paA + kx0;        const char* pa0k1 = paA + (kx0 ^ 64);
    const char* pa1k0 = pa0k0 + BUF;      const char* pa1k1 = pa0k1 + BUF;
    const char* pb0k0 = paB + kx0;        const char* pb0k1 = paB + (kx0 ^ 64);
    const char* pb1k0 = pb0k0 + BUF;      const char* pb1k1 = pb0k1 + BUF;

    bf16x8 a[4][2], b0[NH][2], b1[NH][2];

    auto LDA = [&](const char* p0, const char* p1, int mq) {
#pragma unroll
        for (int mi = 0; mi < 4; mi++) {
            a[mi][0] = *(const bf16x8*)(p0 + mq * 8192 + mi * 2048);
            a[mi][1] = *(const bf16x8*)(p1 + mq * 8192 + mi * 2048);
        }
    };
    auto LDB = [&](const char* p0, const char* p1, int nq, bf16x8 (&bb)[NH][2]) {
#pragma unroll
        for (int ni = 0; ni < NH; ni++) {
            bb[ni][0] = *(const bf16x8*)(p0 + (nq * (BN / 8) + ni * 16) * 128);
            bb[ni][1] = *(const bf16x8*)(p1 + (nq * (BN / 8) + ni * 16) * 128);
        }
    };

    f32x4 acc[8][NI];

    auto MMQ = [&](int mq, int nq, bf16x8 (&bb)[NH][2]) {
        __builtin_amdgcn_s_setprio(1);
#pragma unroll
        for (int mi = 0; mi < 4; mi++)
#pragma unroll
            for (int ni = 0; ni < NH; ni++) {
                f32x4& c = acc[mq * 4 + mi][nq * NH + ni];
                c = __builtin_amdgcn_mfma_f32_16x16x32_bf16(a[mi][0], bb[ni][0], c, 0, 0, 0);
                c = __builtin_amdgcn_mfma_f32_16x16x32_bf16(a[mi][1], bb[ni][1], c, 0, 0, 0);
            }
        __builtin_amdgcn_s_setprio(0);
    };

#define MIDBAR()  __builtin_amdgcn_s_barrier();                                      \
                  asm volatile("s_waitcnt lgkmcnt(0)" ::: "memory")
#define ENDBAR()  __builtin_amdgcn_s_barrier()
#define LGHINT()  asm volatile("s_waitcnt lgkmcnt(8)" ::: "memory")

    const int NT   = K / BK;
    const int NTm1 = NT - 1;

    // prologue: straight-line stage T0 {A0,A1,B0,B1}, T1 {A0,B0,B1};
    // preload pipeline regs: gO = A1(T1) for ph1, gE = A0(T2) for ph2.
    f32x4 gO[4], gE[4];
    {
        f32x4 t0[4];
        LD_A(0, 0, t0); WR_A(0, dA0, t0);
        LD_A(1, 0, t0); WR_A(1, dA0, t0);
        LD_B(0, 0, t0); WR_B(0, dB0, t0);
        LD_B(1, 0, t0); WR_B(1, dB0, t0);
        LD_A(0, 1, t0); WR_A(0, dA1, t0);
        LD_B(0, 1, t0); WR_B(0, dB1, t0);
        LD_B(1, 1, t0); WR_B(1, dB1, t0);
    }
    LD_A(1, 1, gO);
    LD_A(0, (2 < NT ? 2 : NTm1), gE);
#pragma unroll
    for (int i = 0; i < 8; i++)
#pragma unroll
        for (int j = 0; j < NI; j++) acc[i][j] = f32x4{0.f, 0.f, 0.f, 0.f};
    asm volatile("s_waitcnt lgkmcnt(0)" ::: "memory");
    __builtin_amdgcn_s_barrier();

    const int NW = NT / 2;
    for (int ww = 0; ww < NW; ++ww) {
        const int T = 2 * ww;
        const int kt2 = (T + 2 < NT) ? T + 2 : NTm1;
        const int kt3 = (T + 3 < NT) ? T + 3 : NTm1;
        const int kt4 = (T + 4 < NT) ? T + 4 : NTm1;

        // ---- buf0 half: tile T ----
        LDA(pa0k0, pa0k1, 0); LDB(pb0k0, pb0k1, 0, b0); LGHINT();
        MIDBAR();
        WR_A(1, dA1, gO); LD_B(0, kt2, gO);          // ph1: write A1(T+1)
        MMQ(0, 0, b0); ENDBAR();
        LDB(pb0k0, pb0k1, 1, b1);
        MIDBAR();
        WR_A(0, dA0, gE); LD_B(1, kt2, gE);          // ph2: write A0(T+2)
        MMQ(0, 1, b1); ENDBAR();
        LDA(pa0k0, pa0k1, 1);
        MIDBAR();
        WR_B(0, dB0, gO); LD_A(1, kt2, gO);          // ph3: write B0(T+2)
        MMQ(1, 1, b1); ENDBAR();
        MIDBAR();
        WR_B(1, dB0, gE); LD_A(0, kt3, gE);          // ph4: write B1(T+2)
        MMQ(1, 0, b0); ENDBAR();
        // ---- buf1 half: tile T+1 ----
        LDA(pa1k0, pa1k1, 0); LDB(pb1k0, pb1k1, 0, b0); LGHINT();
        MIDBAR();
        WR_A(1, dA0, gO); LD_B(0, kt3, gO);          // ph5: write A1(T+2)
        MMQ(0, 0, b0); ENDBAR();
        LDB(pb1k0, pb1k1, 1, b1);
        MIDBAR();
        WR_A(0, dA1, gE); LD_B(1, kt3, gE);          // ph6: write A0(T+3)
        MMQ(0, 1, b1); ENDBAR();
        LDA(pa1k0, pa1k1, 1);
        MIDBAR();
        WR_B(0, dB1, gO); LD_A(1, kt3, gO);          // ph7: write B0(T+3)
        MMQ(1, 1, b1); ENDBAR();
        MIDBAR();
        WR_B(1, dB1, gE); LD_A(0, kt4, gE);          // ph8: write B1(T+3)
        MMQ(1, 0, b0); ENDBAR();
    }

    // epilogue: gelu -> bf16; C/D layout col = lane&15, row = (lane>>4)*4 + r
    const int r0 = m0 + wr * 128 + fq * 4;
    const int c0 = n0 + wc * (BN / 4) + fr;
    unsigned short* C = Cout + (size_t)e * M * N;
#pragma unroll
    for (int mi = 0; mi < 8; mi++)
#pragma unroll
        for (int ni = 0; ni < NI; ni++) {
            int row = r0 + mi * 16, col = c0 + ni * 16;
#pragma unroll
            for (int r = 0; r < 4; r++)
                C[(size_t)(row + r) * N + col] = f2bf(gelu_tanh(acc[mi][ni][r]));
        }
#undef MIDBAR
#undef ENDBAR
#undef LGHINT
}

// ---------- 8-phase GEMM-BT (R11, proven) for GEMM2 ------------------------

template <int BN, int GX, int GY, bool GELU>
__global__ __launch_bounds__(512, 2)
void gemm8p(const unsigned short* __restrict__ A,
            const unsigned short* __restrict__ B,
            void* __restrict__ Cout, int M, int N, int K) {
    constexpr int BM = 256, BK = 64;
    constexpr int NH = BN / 128;
    constexpr int NI = 2 * NH;
    constexpr int LB = BN / 128;
    constexpr int S  = BN / 8;
    constexpr int ABYTES = BM * BK * 2;
    constexpr int BBYTES = BN * BK * 2;
    constexpr int BUF = ABYTES + BBYTES;
    constexpr int VMC = 2 + 2 * LB;
    constexpr int NWG = NE * GX * GY;

    __shared__ __align__(16) char lds[2 * BUF];

    const int lin = blockIdx.x;
    const int wid = (lin & 7) * (NWG >> 3) + (lin >> 3);
    const int e   = wid / (GX * GY);
    const int rem = wid % (GX * GY);
    const int m0  = (rem % GX) * BM;
    const int n0  = (rem / GX) * BN;

    const size_t K2 = (size_t)K * 2;
    const char* Ae = (const char*)(A + (size_t)e * M * K);
    const char* Be = (const char*)(B + (size_t)e * N * K);

    const int tid  = threadIdx.x;
    const int lane = tid & 63;
    const int w    = tid >> 6;
    const int wr   = w >> 2, wc = w & 3;
    const int fr   = lane & 15, fq = lane >> 4;

    const int rA  = tid >> 3;
    const int kb  = (tid & 7) * 16;
    const int kbs = kb ^ ((rA & 7) << 4);
    const char* aptr = Ae + (size_t)(m0 + rA) * K2 + kbs;
    const int   fB   = (rA / S) * 2 * S + (rA % S);
    const char* bptr = Be + (size_t)(n0 + fB) * K2 + kbs;
    char* dA0 = lds + rA * 128 + kb;
    char* dA1 = dA0 + BUF;
    char* dB0 = lds + ABYTES + fB * 128 + kb;
    char* dB1 = dB0 + BUF;

    auto SA = [&](int au, int kt, char* d) {
        const char* s = aptr + (size_t)kt * 128;
#pragma unroll
        for (int i = 0; i < 2; i++)
            gload_lds16(s + (size_t)(au * 64 + i * 128) * K2,
                        d + (au * 64 + i * 128) * 128);
    };
    auto SB = [&](int bu, int kt, char* d) {
        const char* s = bptr + (size_t)kt * 128;
#pragma unroll
        for (int i = 0; i < LB; i++)
            gload_lds16(s + (size_t)(bu * S + i * 128) * K2,
                        d + (bu * S + i * 128) * 128);
    };

    const int kx0 = (fq * 16) ^ ((lane & 7) << 4);
    const char* paA = lds + (wr * 128 + fr) * 128;
    const char* paB = lds + ABYTES + (wc * (BN / 4) + fr) * 128;
    const char* pa0k0 = paA + kx0;        const char* pa0k1 = paA + (kx0 ^ 64);
    const char* pa1k0 = pa0k0 + BUF;      const char* pa1k1 = pa0k1 + BUF;
    const char* pb0k0 = paB + kx0;        const char* pb0k1 = paB + (kx0 ^ 64);
    const char* pb1k0 = pb0k0 + BUF;      const char* pb1k1 = pb0k1 + BUF;

    f32x4 acc[8][NI];
#pragma unroll
    for (int i = 0; i < 8; i++)
#pragma unroll
        for (int j = 0; j < NI; j++) acc[i][j] = f32x4{0.f, 0.f, 0.f, 0.f};

    bf16x8 a[4][2], b0[NH][2], b1[NH][2];

    auto LDA = [&](const char* p0, const char* p1, int mq) {
#pragma unroll
        for (int mi = 0; mi < 4; mi++) {
            a[mi][0] = *(const bf16x8*)(p0 + mq * 8192 + mi * 2048);
            a[mi][1] = *(const bf16x8*)(p1 + mq * 8192 + mi * 2048);
        }
    };
    auto LDB = [&](const char* p0, const char* p1, int nq, bf16x8 (&bb)[NH][2]) {
#pragma unroll
        for (int ni = 0; ni < NH; ni++) {
            bb[ni][0] = *(const bf16x8*)(p0 + (nq * (BN / 8) + ni * 16) * 128);
            bb[ni][1] = *(const bf16x8*)(p1 + (nq * (BN / 8) + ni * 16) * 128);
        }
    };
    auto MMQ = [&](int mq, int nq, bf16x8 (&bb)[NH][2]) {
        __builtin_amdgcn_s_setprio(1);
#pragma unroll
        for (int mi = 0; mi < 4; mi++)
#pragma unroll
            for (int ni = 0; ni < NH; ni++) {
                f32x4& c = acc[mq * 4 + mi][nq * NH + ni];
                c = __builtin_amdgcn_mfma_f32_16x16x32_bf16(a[mi][0], bb[ni][0], c, 0, 0, 0);
                c = __builtin_amdgcn_mfma_f32_16x16x32_bf16(a[mi][1], bb[ni][1], c, 0, 0, 0);
            }
        __builtin_amdgcn_s_setprio(0);
    };

#define MIDBAR()  __builtin_amdgcn_s_barrier();                                      \
                  asm volatile("s_waitcnt lgkmcnt(0)" ::: "memory")
#define ENDBAR()  __builtin_amdgcn_s_barrier()
#define LGHINT()  asm volatile("s_waitcnt lgkmcnt(8)" ::: "memory")
#define VMW()     asm volatile("s_waitcnt vmcnt(%0)" :: "n"(VMC) : "memory")

    const int NT   = K / BK;
    const int NTm1 = NT - 1;

    SA(0, 0, dA0); SB(0, 0, dB0); SB(1, 0, dB0); SA(1, 0, dA0);
    SA(0, 1, dA1); SB(0, 1, dB1); SB(1, 1, dB1);
    VMW();
    __builtin_amdgcn_s_barrier();

    const int NW = NT / 2;
    for (int ww = 0; ww < NW; ++ww) {
        const int T = 2 * ww;
        const int kt1 = T + 1;
        const int kt2 = (T + 2 < NT) ? T + 2 : NTm1;
        const int kt3 = (T + 3 < NT) ? T + 3 : NTm1;

        LDA(pa0k0, pa0k1, 0); LDB(pb0k0, pb0k1, 0, b0); SA(1, kt1, dA1); LGHINT();
        MIDBAR(); MMQ(0, 0, b0); ENDBAR();
        LDB(pb0k0, pb0k1, 1, b1); SA(0, kt2, dA0);
        MIDBAR(); MMQ(0, 1, b1); ENDBAR();
        LDA(pa0k0, pa0k1, 1); SB(0, kt2, dB0);
        MIDBAR(); MMQ(1, 1, b1); ENDBAR();
        SB(1, kt2, dB0);
        MIDBAR(); MMQ(1, 0, b0); VMW(); ENDBAR();
        LDA(pa1k0, pa1k1, 0); LDB(pb1k0, pb1k1, 0, b0); SA(1, kt2, dA0); LGHINT();
        MIDBAR(); MMQ(0, 0, b0); ENDBAR();
        LDB(pb1k0, pb1k1, 1, b1); SA(0, kt3, dA1);
        MIDBAR(); MMQ(0, 1, b1); ENDBAR();
        LDA(pa1k0, pa1k1, 1); SB(0, kt3, dB1);
        MIDBAR(); MMQ(1, 1, b1); ENDBAR();
        SB(1, kt3, dB1);
        MIDBAR(); MMQ(1, 0, b0); VMW(); ENDBAR();
    }
    asm volatile("s_waitcnt vmcnt(0)" ::: "memory");

    const int r0 = m0 + wr * 128 + fq * 4;
    const int c0 = n0 + wc * (BN / 4) + fr;
    if constexpr (GELU) {
        unsigned short* C = (unsigned short*)Cout + (size_t)e * M * N;
#pragma unroll
        for (int mi = 0; mi < 8; mi++)
#pragma unroll
            for (int ni = 0; ni < NI; ni++) {
                int row = r0 + mi * 16, col = c0 + ni * 16;
#pragma unroll
                for (int r = 0; r < 4; r++)
                    C[(size_t)(row + r) * N + col] = f2bf(gelu_tanh(acc[mi][ni][r]));
            }
    } else {
        float* C = (float*)Cout + (size_t)e * M * N;
#pragma unroll
        for (int mi = 0; mi < 8; mi++)
#pragma unroll
            for (int ni = 0; ni < NI; ni++) {
                int row = r0 + mi * 16, col = c0 + ni * 16;
#pragma unroll
                for (int r = 0; r < 4; r++)
                    C[(size_t)(row + r) * N + col] = acc[mi][ni][r];
            }
    }
#undef MIDBAR
#undef ENDBAR
#undef LGHINT
#undef VMW
}

// ---------- fallback: fused fp32, zero workspace (correctness insurance) ----------

__global__ void fused_fallback(const float* __restrict__ x,
                               const float* __restrict__ w1,
                               const float* __restrict__ w2,
                               float* __restrict__ out) {
    __shared__ float xs[HID];
    __shared__ float hs[FFN];
    const int tok = blockIdx.x;
    const int e   = tok / TPE;
    const float* w1e = w1 + (size_t)e * FFN * HID;
    const float* w2e = w2 + (size_t)e * FFN * HID;
    const int t = threadIdx.x;
    for (int i = t; i < HID; i += 256) xs[i] = x[(size_t)tok * HID + i];
    __syncthreads();
    for (int f = t; f < FFN; f += 256) {
        const float* wr_ = w1e + (size_t)f * HID;
        float s = 0.f;
        for (int k = 0; k < HID; k++) s += xs[k] * wr_[k];
        hs[f] = gelu_tanh(s);
    }
    __syncthreads();
    for (int h = t; h < HID; h += 256) {
        float s = 0.f;
        for (int f = 0; f < FFN; f++) s += hs[f] * w2e[(size_t)f * HID + h];
        out[(size_t)tok * HID + h] = s;
    }
}

// ---------- launch ----------

extern "C" void kernel_launch(void* const* d_in, const int* in_sizes, int n_in,
                              void* d_out, int out_size, void* d_ws, size_t ws_size,
                              hipStream_t stream) {
    const float* x  = (const float*)d_in[0];
    const float* w1 = (const float*)d_in[1];
    const float* w2 = (const float*)d_in[2];
    float* out = (float*)d_out;

    const size_t W2B = (size_t)NE * FFN * HID * 2;   // 64 MB  bf16 w2t
    const size_t HB  = (size_t)TOK * FFN * 2;        // 64 MB  bf16 h
    const size_t need = W2B + HB;                    // 128 MB

    if (ws_size >= need) {
        char* ws = (char*)d_ws;
        unsigned short* w2t = (unsigned short*)ws;
        unsigned short* hb  = (unsigned short*)(ws + W2B);

        // prep: only w2 transpose-convert (192 MB traffic)
        transpose_cvt<<<dim3(FFN / 64, HID / 64, NE), 256, 0, stream>>>(w2, w2t);

        // GEMM1 fused-cvt: h = gelu(x @ w1^T), f32 inputs -> 512 blocks
        gemm8f<TPE / 256, FFN / 256><<<NE * (TPE / 256) * (FFN / 256), 512, 0, stream>>>(
            x, w1, hb, TPE, FFN, HID);
        // GEMM2: out = h @ w2t^T -> 256 blocks (R11 proven 8-phase)
        gemm8p<128, TPE / 256, HID / 128, false><<<NE * (TPE / 256) * (HID / 128), 512, 0, stream>>>(
            hb, w2t, out, TPE, HID, FFN);
    } else {
        fused_fallback<<<TOK, 256, 0, stream>>>(x, w1, w2, out);
    }
}

// Round 17
// 234.172 us; speedup vs baseline: 1.3609x; 1.2530x over previous
//
#include <hip/hip_runtime.h>
#include <hip/hip_bf16.h>
#include <stdint.h>

#define NE 8
#define HID 1024
#define FFN 4096
#define TOK 8192
#define TPE (TOK / NE)   // 1024 tokens per expert

typedef __attribute__((ext_vector_type(8))) short    bf16x8;
typedef __attribute__((ext_vector_type(4))) float    f32x4;
typedef __attribute__((ext_vector_type(4))) unsigned short ushort4v;
typedef __attribute__((ext_vector_type(8))) unsigned short ushort8v;

// ---------- helpers ----------

__device__ __forceinline__ unsigned short f2bf(float f) {
    union { float f; unsigned u; } c; c.f = f;
    unsigned r = c.u + 0x7fffu + ((c.u >> 16) & 1u);   // RNE, inputs finite
    return (unsigned short)(r >> 16);
}

__device__ __forceinline__ float gelu_tanh(float x) {
    const float c0 = 0.7978845608028654f;  // sqrt(2/pi)
    const float c1 = 0.044715f;
    float u = c0 * (x + c1 * x * x * x);
    float t = 1.0f - 2.0f / (1.0f + __expf(2.0f * u));
    return 0.5f * x * (1.0f + t);
}

typedef const __attribute__((address_space(1))) void gbl_void_t;
typedef __attribute__((address_space(3))) void lds_void_t;

__device__ __forceinline__ void gload_lds16(const void* g, void* l) {
    __builtin_amdgcn_global_load_lds((gbl_void_t*)g, (lds_void_t*)l, 16, 0, 0);
}

// ---------- prep: transpose-convert w2 [E][F][H] f32 -> w2t [E][H][F] bf16 ----

__global__ void transpose_cvt(const float* __restrict__ in,
                              unsigned short* __restrict__ out) {
    __shared__ unsigned short tile[64][65];
    const int e  = blockIdx.z;
    const int f0 = blockIdx.x * 64;
    const int h0 = blockIdx.y * 64;
    const float*     src = in  + (size_t)e * FFN * HID;
    unsigned short*  dst = out + (size_t)e * HID * FFN;
    const int t  = threadIdx.x;
    const int tr = t >> 4;        // 0..15
    const int tc = (t & 15) * 4;  // 0..60
#pragma unroll
    for (int i = 0; i < 4; i++) {
        int f = i * 16 + tr;
        f32x4 v = *(const f32x4*)(src + (size_t)(f0 + f) * HID + h0 + tc);
#pragma unroll
        for (int j = 0; j < 4; j++) tile[f][tc + j] = f2bf(v[j]);
    }
    __syncthreads();
#pragma unroll
    for (int i = 0; i < 4; i++) {
        int h = i * 16 + tr;
        ushort4v o;
#pragma unroll
        for (int j = 0; j < 4; j++) o[j] = tile[tc + j][h];
        *(ushort4v*)(dst + (size_t)(h0 + h) * FFN + f0 + tc) = o;
    }
}

// ---------- GEMM1 fused-cvt: C=gelu(x@w1^T), f32 inputs, 8-phase R11 skeleton
// Staging = reg-stage: f32 loads issued 2 phases ahead -> f2bf cvt ->
// ds_write_b128 (swizzled dest, per-lane). Writes placed AFTER MIDBAR's
// "memory" asm; every LDS region's readers retire at their own lgkm0 BEFORE
// the barrier the write follows. R14 exact source (best: 231.8 us) — both
// cvt_pk variants (R15 asm, R16 intrinsic) spilled and regressed.

template <int GX, int GY>
__global__ __launch_bounds__(512, 2)
void gemm8f(const float* __restrict__ Af,
            const float* __restrict__ Bf,
            unsigned short* __restrict__ Cout, int M, int N, int K) {
    constexpr int BM = 256, BN = 256, BK = 64;
    constexpr int NH = 2, NI = 4, S = 32;
    constexpr int ABYTES = BM * BK * 2;   // 32768
    constexpr int BBYTES = BN * BK * 2;   // 32768
    constexpr int BUF = ABYTES + BBYTES;
    constexpr int NWG = NE * GX * GY;

    __shared__ __align__(16) char lds[2 * BUF];

    const int lin = blockIdx.x;
    const int wid = (lin & 7) * (NWG >> 3) + (lin >> 3);
    const int e   = wid / (GX * GY);
    const int rem = wid % (GX * GY);
    const int m0  = (rem % GX) * BM;
    const int n0  = (rem / GX) * BN;

    const float* Ae = Af + (size_t)e * M * K;
    const float* Be = Bf + (size_t)e * N * K;

    const int tid  = threadIdx.x;
    const int lane = tid & 63;
    const int w    = tid >> 6;
    const int wr   = w >> 2, wc = w & 3;
    const int fr   = lane & 15, fq = lane >> 4;

    // ---- staging addressing ----
    const int rA  = tid >> 3;             // 0..63
    const int kb  = (tid & 7) * 16;       // bf16-byte offset in 128B row
    const int kbs = kb ^ ((rA & 7) << 4); // swizzled bf16-byte offset
    const int eoff = kbs >> 1;            // f32 element offset (0..63, mult of 8)
    const float* aFb = Ae + (size_t)(m0 + rA) * K + eoff;
    const int   fB   = (rA / S) * 2 * S + (rA % S);
    const float* bFb = Be + (size_t)(n0 + fB) * K + eoff;
    char* dA0 = lds + rA * 128 + kb;
    char* dA1 = dA0 + BUF;
    char* dB0 = lds + ABYTES + fB * 128 + kb;
    char* dB1 = dB0 + BUF;

    auto LD_A = [&](int au, int kt, f32x4 (&g)[4]) {
        const float* s = aFb + (size_t)kt * 64;
        g[0] = *(const f32x4*)(s + (size_t)(au * 64) * K);
        g[1] = *(const f32x4*)(s + (size_t)(au * 64) * K + 4);
        g[2] = *(const f32x4*)(s + (size_t)(au * 64 + 128) * K);
        g[3] = *(const f32x4*)(s + (size_t)(au * 64 + 128) * K + 4);
    };
    auto LD_B = [&](int bu, int kt, f32x4 (&g)[4]) {
        const float* s = bFb + (size_t)kt * 64;
        g[0] = *(const f32x4*)(s + (size_t)(bu * S) * K);
        g[1] = *(const f32x4*)(s + (size_t)(bu * S) * K + 4);
        g[2] = *(const f32x4*)(s + (size_t)(bu * S + 128) * K);
        g[3] = *(const f32x4*)(s + (size_t)(bu * S + 128) * K + 4);
    };
    auto PACK = [&](const f32x4& lo, const f32x4& hi) {
        ushort8v o;
#pragma unroll
        for (int j = 0; j < 4; j++) { o[j] = f2bf(lo[j]); o[4 + j] = f2bf(hi[j]); }
        return o;
    };
    auto WR_A = [&](int au, char* d, f32x4 (&g)[4]) {
        *(ushort8v*)(d + (au * 64) * 128)       = PACK(g[0], g[1]);
        *(ushort8v*)(d + (au * 64 + 128) * 128) = PACK(g[2], g[3]);
    };
    auto WR_B = [&](int bu, char* d, f32x4 (&g)[4]) {
        *(ushort8v*)(d + (bu * S) * 128)        = PACK(g[0], g[1]);
        *(ushort8v*)(d + (bu * S + 128) * 128)  = PACK(g[2], g[3]);
    };

    // ---- LDS read bases (swizzled, identical to R11) ----
    const int kx0 = (fq * 16) ^ ((lane & 7) << 4);
    const char* paA = lds + (wr * 128 + fr) * 128;
    const char* paB = lds + ABYTES + (wc * (BN / 4) + fr) * 128;
    const char* pa0k0 = paA + kx0;        const char* pa0k1 = paA + (kx0 ^ 64);
    const char* pa1k0 = pa0k0 + BUF;      const char* pa1k1 = pa0k1 + BUF;
    const char* pb0k0 = paB + kx0;        const char* pb0k1 = paB + (kx0 ^ 64);
    const char* pb1k0 = pb0k0 + BUF;      const char* pb1k1 = pb0k1 + BUF;

    bf16x8 a[4][2], b0[NH][2], b1[NH][2];

    auto LDA = [&](const char* p0, const char* p1, int mq) {
#pragma unroll
        for (int mi = 0; mi < 4; mi++) {
            a[mi][0] = *(const bf16x8*)(p0 + mq * 8192 + mi * 2048);
            a[mi][1] = *(const bf16x8*)(p1 + mq * 8192 + mi * 2048);
        }
    };
    auto LDB = [&](const char* p0, const char* p1, int nq, bf16x8 (&bb)[NH][2]) {
#pragma unroll
        for (int ni = 0; ni < NH; ni++) {
            bb[ni][0] = *(const bf16x8*)(p0 + (nq * (BN / 8) + ni * 16) * 128);
            bb[ni][1] = *(const bf16x8*)(p1 + (nq * (BN / 8) + ni * 16) * 128);
        }
    };

    f32x4 acc[8][NI];

    auto MMQ = [&](int mq, int nq, bf16x8 (&bb)[NH][2]) {
        __builtin_amdgcn_s_setprio(1);
#pragma unroll
        for (int mi = 0; mi < 4; mi++)
#pragma unroll
            for (int ni = 0; ni < NH; ni++) {
                f32x4& c = acc[mq * 4 + mi][nq * NH + ni];
                c = __builtin_amdgcn_mfma_f32_16x16x32_bf16(a[mi][0], bb[ni][0], c, 0, 0, 0);
                c = __builtin_amdgcn_mfma_f32_16x16x32_bf16(a[mi][1], bb[ni][1], c, 0, 0, 0);
            }
        __builtin_amdgcn_s_setprio(0);
    };

#define MIDBAR()  __builtin_amdgcn_s_barrier();                                      \
                  asm volatile("s_waitcnt lgkmcnt(0)" ::: "memory")
#define ENDBAR()  __builtin_amdgcn_s_barrier()
#define LGHINT()  asm volatile("s_waitcnt lgkmcnt(8)" ::: "memory")

    const int NT   = K / BK;
    const int NTm1 = NT - 1;

    // prologue: straight-line stage T0 {A0,A1,B0,B1}, T1 {A0,B0,B1};
    // preload pipeline regs: gO = A1(T1) for ph1, gE = A0(T2) for ph2.
    f32x4 gO[4], gE[4];
    {
        f32x4 t0[4];
        LD_A(0, 0, t0); WR_A(0, dA0, t0);
        LD_A(1, 0, t0); WR_A(1, dA0, t0);
        LD_B(0, 0, t0); WR_B(0, dB0, t0);
        LD_B(1, 0, t0); WR_B(1, dB0, t0);
        LD_A(0, 1, t0); WR_A(0, dA1, t0);
        LD_B(0, 1, t0); WR_B(0, dB1, t0);
        LD_B(1, 1, t0); WR_B(1, dB1, t0);
    }
    LD_A(1, 1, gO);
    LD_A(0, (2 < NT ? 2 : NTm1), gE);
#pragma unroll
    for (int i = 0; i < 8; i++)
#pragma unroll
        for (int j = 0; j < NI; j++) acc[i][j] = f32x4{0.f, 0.f, 0.f, 0.f};
    asm volatile("s_waitcnt lgkmcnt(0)" ::: "memory");
    __builtin_amdgcn_s_barrier();

    const int NW = NT / 2;
    for (int ww = 0; ww < NW; ++ww) {
        const int T = 2 * ww;
        const int kt2 = (T + 2 < NT) ? T + 2 : NTm1;
        const int kt3 = (T + 3 < NT) ? T + 3 : NTm1;
        const int kt4 = (T + 4 < NT) ? T + 4 : NTm1;

        // ---- buf0 half: tile T ----
        LDA(pa0k0, pa0k1, 0); LDB(pb0k0, pb0k1, 0, b0); LGHINT();
        MIDBAR();
        WR_A(1, dA1, gO); LD_B(0, kt2, gO);          // ph1: write A1(T+1)
        MMQ(0, 0, b0); ENDBAR();
        LDB(pb0k0, pb0k1, 1, b1);
        MIDBAR();
        WR_A(0, dA0, gE); LD_B(1, kt2, gE);          // ph2: write A0(T+2)
        MMQ(0, 1, b1); ENDBAR();
        LDA(pa0k0, pa0k1, 1);
        MIDBAR();
        WR_B(0, dB0, gO); LD_A(1, kt2, gO);          // ph3: write B0(T+2)
        MMQ(1, 1, b1); ENDBAR();
        MIDBAR();
        WR_B(1, dB0, gE); LD_A(0, kt3, gE);          // ph4: write B1(T+2)
        MMQ(1, 0, b0); ENDBAR();
        // ---- buf1 half: tile T+1 ----
        LDA(pa1k0, pa1k1, 0); LDB(pb1k0, pb1k1, 0, b0); LGHINT();
        MIDBAR();
        WR_A(1, dA0, gO); LD_B(0, kt3, gO);          // ph5: write A1(T+2)
        MMQ(0, 0, b0); ENDBAR();
        LDB(pb1k0, pb1k1, 1, b1);
        MIDBAR();
        WR_A(0, dA1, gE); LD_B(1, kt3, gE);          // ph6: write A0(T+3)
        MMQ(0, 1, b1); ENDBAR();
        LDA(pa1k0, pa1k1, 1);
        MIDBAR();
        WR_B(0, dB1, gO); LD_A(1, kt3, gO);          // ph7: write B0(T+3)
        MMQ(1, 1, b1); ENDBAR();
        MIDBAR();
        WR_B(1, dB1, gE); LD_A(0, kt4, gE);          // ph8: write B1(T+3)
        MMQ(1, 0, b0); ENDBAR();
    }

    // epilogue: gelu -> bf16; C/D layout col = lane&15, row = (lane>>4)*4 + r
    const int r0 = m0 + wr * 128 + fq * 4;
    const int c0 = n0 + wc * (BN / 4) + fr;
    unsigned short* C = Cout + (size_t)e * M * N;
#pragma unroll
    for (int mi = 0; mi < 8; mi++)
#pragma unroll
        for (int ni = 0; ni < NI; ni++) {
            int row = r0 + mi * 16, col = c0 + ni * 16;
#pragma unroll
            for (int r = 0; r < 4; r++)
                C[(size_t)(row + r) * N + col] = f2bf(gelu_tanh(acc[mi][ni][r]));
        }
#undef MIDBAR
#undef ENDBAR
#undef LGHINT
}

// ---------- 8-phase GEMM-BT (R11, proven) for GEMM2 ------------------------

template <int BN, int GX, int GY, bool GELU>
__global__ __launch_bounds__(512, 2)
void gemm8p(const unsigned short* __restrict__ A,
            const unsigned short* __restrict__ B,
            void* __restrict__ Cout, int M, int N, int K) {
    constexpr int BM = 256, BK = 64;
    constexpr int NH = BN / 128;
    constexpr int NI = 2 * NH;
    constexpr int LB = BN / 128;
    constexpr int S  = BN / 8;
    constexpr int ABYTES = BM * BK * 2;
    constexpr int BBYTES = BN * BK * 2;
    constexpr int BUF = ABYTES + BBYTES;
    constexpr int VMC = 2 + 2 * LB;
    constexpr int NWG = NE * GX * GY;

    __shared__ __align__(16) char lds[2 * BUF];

    const int lin = blockIdx.x;
    const int wid = (lin & 7) * (NWG >> 3) + (lin >> 3);
    const int e   = wid / (GX * GY);
    const int rem = wid % (GX * GY);
    const int m0  = (rem % GX) * BM;
    const int n0  = (rem / GX) * BN;

    const size_t K2 = (size_t)K * 2;
    const char* Ae = (const char*)(A + (size_t)e * M * K);
    const char* Be = (const char*)(B + (size_t)e * N * K);

    const int tid  = threadIdx.x;
    const int lane = tid & 63;
    const int w    = tid >> 6;
    const int wr   = w >> 2, wc = w & 3;
    const int fr   = lane & 15, fq = lane >> 4;

    const int rA  = tid >> 3;
    const int kb  = (tid & 7) * 16;
    const int kbs = kb ^ ((rA & 7) << 4);
    const char* aptr = Ae + (size_t)(m0 + rA) * K2 + kbs;
    const int   fB   = (rA / S) * 2 * S + (rA % S);
    const char* bptr = Be + (size_t)(n0 + fB) * K2 + kbs;
    char* dA0 = lds + rA * 128 + kb;
    char* dA1 = dA0 + BUF;
    char* dB0 = lds + ABYTES + fB * 128 + kb;
    char* dB1 = dB0 + BUF;

    auto SA = [&](int au, int kt, char* d) {
        const char* s = aptr + (size_t)kt * 128;
#pragma unroll
        for (int i = 0; i < 2; i++)
            gload_lds16(s + (size_t)(au * 64 + i * 128) * K2,
                        d + (au * 64 + i * 128) * 128);
    };
    auto SB = [&](int bu, int kt, char* d) {
        const char* s = bptr + (size_t)kt * 128;
#pragma unroll
        for (int i = 0; i < LB; i++)
            gload_lds16(s + (size_t)(bu * S + i * 128) * K2,
                        d + (bu * S + i * 128) * 128);
    };

    const int kx0 = (fq * 16) ^ ((lane & 7) << 4);
    const char* paA = lds + (wr * 128 + fr) * 128;
    const char* paB = lds + ABYTES + (wc * (BN / 4) + fr) * 128;
    const char* pa0k0 = paA + kx0;        const char* pa0k1 = paA + (kx0 ^ 64);
    const char* pa1k0 = pa0k0 + BUF;      const char* pa1k1 = pa0k1 + BUF;
    const char* pb0k0 = paB + kx0;        const char* pb0k1 = paB + (kx0 ^ 64);
    const char* pb1k0 = pb0k0 + BUF;      const char* pb1k1 = pb0k1 + BUF;

    f32x4 acc[8][NI];
#pragma unroll
    for (int i = 0; i < 8; i++)
#pragma unroll
        for (int j = 0; j < NI; j++) acc[i][j] = f32x4{0.f, 0.f, 0.f, 0.f};

    bf16x8 a[4][2], b0[NH][2], b1[NH][2];

    auto LDA = [&](const char* p0, const char* p1, int mq) {
#pragma unroll
        for (int mi = 0; mi < 4; mi++) {
            a[mi][0] = *(const bf16x8*)(p0 + mq * 8192 + mi * 2048);
            a[mi][1] = *(const bf16x8*)(p1 + mq * 8192 + mi * 2048);
        }
    };
    auto LDB = [&](const char* p0, const char* p1, int nq, bf16x8 (&bb)[NH][2]) {
#pragma unroll
        for (int ni = 0; ni < NH; ni++) {
            bb[ni][0] = *(const bf16x8*)(p0 + (nq * (BN / 8) + ni * 16) * 128);
            bb[ni][1] = *(const bf16x8*)(p1 + (nq * (BN / 8) + ni * 16) * 128);
        }
    };
    auto MMQ = [&](int mq, int nq, bf16x8 (&bb)[NH][2]) {
        __builtin_amdgcn_s_setprio(1);
#pragma unroll
        for (int mi = 0; mi < 4; mi++)
#pragma unroll
            for (int ni = 0; ni < NH; ni++) {
                f32x4& c = acc[mq * 4 + mi][nq * NH + ni];
                c = __builtin_amdgcn_mfma_f32_16x16x32_bf16(a[mi][0], bb[ni][0], c, 0, 0, 0);
                c = __builtin_amdgcn_mfma_f32_16x16x32_bf16(a[mi][1], bb[ni][1], c, 0, 0, 0);
            }
        __builtin_amdgcn_s_setprio(0);
    };

#define MIDBAR()  __builtin_amdgcn_s_barrier();                                      \
                  asm volatile("s_waitcnt lgkmcnt(0)" ::: "memory")
#define ENDBAR()  __builtin_amdgcn_s_barrier()
#define LGHINT()  asm volatile("s_waitcnt lgkmcnt(8)" ::: "memory")
#define VMW()     asm volatile("s_waitcnt vmcnt(%0)" :: "n"(VMC) : "memory")

    const int NT   = K / BK;
    const int NTm1 = NT - 1;

    SA(0, 0, dA0); SB(0, 0, dB0); SB(1, 0, dB0); SA(1, 0, dA0);
    SA(0, 1, dA1); SB(0, 1, dB1); SB(1, 1, dB1);
    VMW();
    __builtin_amdgcn_s_barrier();

    const int NW = NT / 2;
    for (int ww = 0; ww < NW; ++ww) {
        const int T = 2 * ww;
        const int kt1 = T + 1;
        const int kt2 = (T + 2 < NT) ? T + 2 : NTm1;
        const int kt3 = (T + 3 < NT) ? T + 3 : NTm1;

        LDA(pa0k0, pa0k1, 0); LDB(pb0k0, pb0k1, 0, b0); SA(1, kt1, dA1); LGHINT();
        MIDBAR(); MMQ(0, 0, b0); ENDBAR();
        LDB(pb0k0, pb0k1, 1, b1); SA(0, kt2, dA0);
        MIDBAR(); MMQ(0, 1, b1); ENDBAR();
        LDA(pa0k0, pa0k1, 1); SB(0, kt2, dB0);
        MIDBAR(); MMQ(1, 1, b1); ENDBAR();
        SB(1, kt2, dB0);
        MIDBAR(); MMQ(1, 0, b0); VMW(); ENDBAR();
        LDA(pa1k0, pa1k1, 0); LDB(pb1k0, pb1k1, 0, b0); SA(1, kt2, dA0); LGHINT();
        MIDBAR(); MMQ(0, 0, b0); ENDBAR();
        LDB(pb1k0, pb1k1, 1, b1); SA(0, kt3, dA1);
        MIDBAR(); MMQ(0, 1, b1); ENDBAR();
        LDA(pa1k0, pa1k1, 1); SB(0, kt3, dB1);
        MIDBAR(); MMQ(1, 1, b1); ENDBAR();
        SB(1, kt3, dB1);
        MIDBAR(); MMQ(1, 0, b0); VMW(); ENDBAR();
    }
    asm volatile("s_waitcnt vmcnt(0)" ::: "memory");

    const int r0 = m0 + wr * 128 + fq * 4;
    const int c0 = n0 + wc * (BN / 4) + fr;
    if constexpr (GELU) {
        unsigned short* C = (unsigned short*)Cout + (size_t)e * M * N;
#pragma unroll
        for (int mi = 0; mi < 8; mi++)
#pragma unroll
            for (int ni = 0; ni < NI; ni++) {
                int row = r0 + mi * 16, col = c0 + ni * 16;
#pragma unroll
                for (int r = 0; r < 4; r++)
                    C[(size_t)(row + r) * N + col] = f2bf(gelu_tanh(acc[mi][ni][r]));
            }
    } else {
        float* C = (float*)Cout + (size_t)e * M * N;
#pragma unroll
        for (int mi = 0; mi < 8; mi++)
#pragma unroll
            for (int ni = 0; ni < NI; ni++) {
                int row = r0 + mi * 16, col = c0 + ni * 16;
#pragma unroll
                for (int r = 0; r < 4; r++)
                    C[(size_t)(row + r) * N + col] = acc[mi][ni][r];
            }
    }
#undef MIDBAR
#undef ENDBAR
#undef LGHINT
#undef VMW
}

// ---------- fallback: fused fp32, zero workspace (correctness insurance) ----------

__global__ void fused_fallback(const float* __restrict__ x,
                               const float* __restrict__ w1,
                               const float* __restrict__ w2,
                               float* __restrict__ out) {
    __shared__ float xs[HID];
    __shared__ float hs[FFN];
    const int tok = blockIdx.x;
    const int e   = tok / TPE;
    const float* w1e = w1 + (size_t)e * FFN * HID;
    const float* w2e = w2 + (size_t)e * FFN * HID;
    const int t = threadIdx.x;
    for (int i = t; i < HID; i += 256) xs[i] = x[(size_t)tok * HID + i];
    __syncthreads();
    for (int f = t; f < FFN; f += 256) {
        const float* wr_ = w1e + (size_t)f * HID;
        float s = 0.f;
        for (int k = 0; k < HID; k++) s += xs[k] * wr_[k];
        hs[f] = gelu_tanh(s);
    }
    __syncthreads();
    for (int h = t; h < HID; h += 256) {
        float s = 0.f;
        for (int f = 0; f < FFN; f++) s += hs[f] * w2e[(size_t)f * HID + h];
        out[(size_t)tok * HID + h] = s;
    }
}

// ---------- launch ----------

extern "C" void kernel_launch(void* const* d_in, const int* in_sizes, int n_in,
                              void* d_out, int out_size, void* d_ws, size_t ws_size,
                              hipStream_t stream) {
    const float* x  = (const float*)d_in[0];
    const float* w1 = (const float*)d_in[1];
    const float* w2 = (const float*)d_in[2];
    float* out = (float*)d_out;

    const size_t W2B = (size_t)NE * FFN * HID * 2;   // 64 MB  bf16 w2t
    const size_t HB  = (size_t)TOK * FFN * 2;        // 64 MB  bf16 h
    const size_t need = W2B + HB;                    // 128 MB

    if (ws_size >= need) {
        char* ws = (char*)d_ws;
        unsigned short* w2t = (unsigned short*)ws;
        unsigned short* hb  = (unsigned short*)(ws + W2B);

        // prep: only w2 transpose-convert (192 MB traffic)
        transpose_cvt<<<dim3(FFN / 64, HID / 64, NE), 256, 0, stream>>>(w2, w2t);

        // GEMM1 fused-cvt: h = gelu(x @ w1^T), f32 inputs -> 512 blocks
        gemm8f<TPE / 256, FFN / 256><<<NE * (TPE / 256) * (FFN / 256), 512, 0, stream>>>(
            x, w1, hb, TPE, FFN, HID);
        // GEMM2: out = h @ w2t^T -> 256 blocks (R11 proven 8-phase)
        gemm8p<128, TPE / 256, HID / 128, false><<<NE * (TPE / 256) * (HID / 128), 512, 0, stream>>>(
            hb, w2t, out, TPE, HID, FFN);
    } else {
        fused_fallback<<<TOK, 256, 0, stream>>>(x, w1, w2, out);
    }
}

// Round 19
// 229.780 us; speedup vs baseline: 1.3869x; 1.0191x over previous
//
#include <hip/hip_runtime.h>
#include <hip/hip_bf16.h>
#include <stdint.h>

#define NE 8
#define HID 1024
#define FFN 4096
#define TOK 8192
#define TPE (TOK / NE)   // 1024 tokens per expert

typedef __attribute__((ext_vector_type(8))) short    bf16x8;
typedef __attribute__((ext_vector_type(4))) float    f32x4;
typedef __attribute__((ext_vector_type(4))) unsigned short ushort4v;
typedef __attribute__((ext_vector_type(8))) unsigned short ushort8v;

// ---------- helpers ----------

__device__ __forceinline__ unsigned short f2bf(float f) {
    union { float f; unsigned u; } c; c.f = f;
    unsigned r = c.u + 0x7fffu + ((c.u >> 16) & 1u);   // RNE, inputs finite
    return (unsigned short)(r >> 16);
}

__device__ __forceinline__ float gelu_tanh(float x) {
    const float c0 = 0.7978845608028654f;  // sqrt(2/pi)
    const float c1 = 0.044715f;
    float u = c0 * (x + c1 * x * x * x);
    float t = 1.0f - 2.0f / (1.0f + __expf(2.0f * u));
    return 0.5f * x * (1.0f + t);
}

typedef const __attribute__((address_space(1))) void gbl_void_t;
typedef __attribute__((address_space(3))) void lds_void_t;

__device__ __forceinline__ void gload_lds16(const void* g, void* l) {
    __builtin_amdgcn_global_load_lds((gbl_void_t*)g, (lds_void_t*)l, 16, 0, 0);
}

// ---------- prep: transpose-convert w2 [E][F][H] f32 -> w2t [E][H][F] bf16 ----

__global__ void transpose_cvt(const float* __restrict__ in,
                              unsigned short* __restrict__ out) {
    __shared__ unsigned short tile[64][65];
    const int e  = blockIdx.z;
    const int f0 = blockIdx.x * 64;
    const int h0 = blockIdx.y * 64;
    const float*     src = in  + (size_t)e * FFN * HID;
    unsigned short*  dst = out + (size_t)e * HID * FFN;
    const int t  = threadIdx.x;
    const int tr = t >> 4;        // 0..15
    const int tc = (t & 15) * 4;  // 0..60
#pragma unroll
    for (int i = 0; i < 4; i++) {
        int f = i * 16 + tr;
        f32x4 v = *(const f32x4*)(src + (size_t)(f0 + f) * HID + h0 + tc);
#pragma unroll
        for (int j = 0; j < 4; j++) tile[f][tc + j] = f2bf(v[j]);
    }
    __syncthreads();
#pragma unroll
    for (int i = 0; i < 4; i++) {
        int h = i * 16 + tr;
        ushort4v o;
#pragma unroll
        for (int j = 0; j < 4; j++) o[j] = tile[tc + j][h];
        *(ushort4v*)(dst + (size_t)(h0 + h) * FFN + f0 + tc) = o;
    }
}

// ---------- GEMM1 fused-cvt: C=gelu(x@w1^T), f32 inputs (R14 exact) --------

template <int GX, int GY>
__global__ __launch_bounds__(512, 2)
void gemm8f(const float* __restrict__ Af,
            const float* __restrict__ Bf,
            unsigned short* __restrict__ Cout, int M, int N, int K) {
    constexpr int BM = 256, BN = 256, BK = 64;
    constexpr int NH = 2, NI = 4, S = 32;
    constexpr int ABYTES = BM * BK * 2;   // 32768
    constexpr int BBYTES = BN * BK * 2;   // 32768
    constexpr int BUF = ABYTES + BBYTES;
    constexpr int NWG = NE * GX * GY;

    __shared__ __align__(16) char lds[2 * BUF];

    const int lin = blockIdx.x;
    const int wid = (lin & 7) * (NWG >> 3) + (lin >> 3);
    const int e   = wid / (GX * GY);
    const int rem = wid % (GX * GY);
    const int m0  = (rem % GX) * BM;
    const int n0  = (rem / GX) * BN;

    const float* Ae = Af + (size_t)e * M * K;
    const float* Be = Bf + (size_t)e * N * K;

    const int tid  = threadIdx.x;
    const int lane = tid & 63;
    const int w    = tid >> 6;
    const int wr   = w >> 2, wc = w & 3;
    const int fr   = lane & 15, fq = lane >> 4;

    const int rA  = tid >> 3;
    const int kb  = (tid & 7) * 16;
    const int kbs = kb ^ ((rA & 7) << 4);
    const int eoff = kbs >> 1;
    const float* aFb = Ae + (size_t)(m0 + rA) * K + eoff;
    const int   fB   = (rA / S) * 2 * S + (rA % S);
    const float* bFb = Be + (size_t)(n0 + fB) * K + eoff;
    char* dA0 = lds + rA * 128 + kb;
    char* dA1 = dA0 + BUF;
    char* dB0 = lds + ABYTES + fB * 128 + kb;
    char* dB1 = dB0 + BUF;

    auto LD_A = [&](int au, int kt, f32x4 (&g)[4]) {
        const float* s = aFb + (size_t)kt * 64;
        g[0] = *(const f32x4*)(s + (size_t)(au * 64) * K);
        g[1] = *(const f32x4*)(s + (size_t)(au * 64) * K + 4);
        g[2] = *(const f32x4*)(s + (size_t)(au * 64 + 128) * K);
        g[3] = *(const f32x4*)(s + (size_t)(au * 64 + 128) * K + 4);
    };
    auto LD_B = [&](int bu, int kt, f32x4 (&g)[4]) {
        const float* s = bFb + (size_t)kt * 64;
        g[0] = *(const f32x4*)(s + (size_t)(bu * S) * K);
        g[1] = *(const f32x4*)(s + (size_t)(bu * S) * K + 4);
        g[2] = *(const f32x4*)(s + (size_t)(bu * S + 128) * K);
        g[3] = *(const f32x4*)(s + (size_t)(bu * S + 128) * K + 4);
    };
    auto PACK = [&](const f32x4& lo, const f32x4& hi) {
        ushort8v o;
#pragma unroll
        for (int j = 0; j < 4; j++) { o[j] = f2bf(lo[j]); o[4 + j] = f2bf(hi[j]); }
        return o;
    };
    auto WR_A = [&](int au, char* d, f32x4 (&g)[4]) {
        *(ushort8v*)(d + (au * 64) * 128)       = PACK(g[0], g[1]);
        *(ushort8v*)(d + (au * 64 + 128) * 128) = PACK(g[2], g[3]);
    };
    auto WR_B = [&](int bu, char* d, f32x4 (&g)[4]) {
        *(ushort8v*)(d + (bu * S) * 128)        = PACK(g[0], g[1]);
        *(ushort8v*)(d + (bu * S + 128) * 128)  = PACK(g[2], g[3]);
    };

    const int kx0 = (fq * 16) ^ ((lane & 7) << 4);
    const char* paA = lds + (wr * 128 + fr) * 128;
    const char* paB = lds + ABYTES + (wc * (BN / 4) + fr) * 128;
    const char* pa0k0 = paA + kx0;        const char* pa0k1 = paA + (kx0 ^ 64);
    const char* pa1k0 = pa0k0 + BUF;      const char* pa1k1 = pa0k1 + BUF;
    const char* pb0k0 = paB + kx0;        const char* pb0k1 = paB + (kx0 ^ 64);
    const char* pb1k0 = pb0k0 + BUF;      const char* pb1k1 = pb0k1 + BUF;

    bf16x8 a[4][2], b0[NH][2], b1[NH][2];

    auto LDA = [&](const char* p0, const char* p1, int mq) {
#pragma unroll
        for (int mi = 0; mi < 4; mi++) {
            a[mi][0] = *(const bf16x8*)(p0 + mq * 8192 + mi * 2048);
            a[mi][1] = *(const bf16x8*)(p1 + mq * 8192 + mi * 2048);
        }
    };
    auto LDB = [&](const char* p0, const char* p1, int nq, bf16x8 (&bb)[NH][2]) {
#pragma unroll
        for (int ni = 0; ni < NH; ni++) {
            bb[ni][0] = *(const bf16x8*)(p0 + (nq * (BN / 8) + ni * 16) * 128);
            bb[ni][1] = *(const bf16x8*)(p1 + (nq * (BN / 8) + ni * 16) * 128);
        }
    };

    f32x4 acc[8][NI];

    auto MMQ = [&](int mq, int nq, bf16x8 (&bb)[NH][2]) {
        __builtin_amdgcn_s_setprio(1);
#pragma unroll
        for (int mi = 0; mi < 4; mi++)
#pragma unroll
            for (int ni = 0; ni < NH; ni++) {
                f32x4& c = acc[mq * 4 + mi][nq * NH + ni];
                c = __builtin_amdgcn_mfma_f32_16x16x32_bf16(a[mi][0], bb[ni][0], c, 0, 0, 0);
                c = __builtin_amdgcn_mfma_f32_16x16x32_bf16(a[mi][1], bb[ni][1], c, 0, 0, 0);
            }
        __builtin_amdgcn_s_setprio(0);
    };

#define MIDBAR()  __builtin_amdgcn_s_barrier();                                      \
                  asm volatile("s_waitcnt lgkmcnt(0)" ::: "memory")
#define ENDBAR()  __builtin_amdgcn_s_barrier()
#define LGHINT()  asm volatile("s_waitcnt lgkmcnt(8)" ::: "memory")

    const int NT   = K / BK;
    const int NTm1 = NT - 1;

    f32x4 gO[4], gE[4];
    {
        f32x4 t0[4];
        LD_A(0, 0, t0); WR_A(0, dA0, t0);
        LD_A(1, 0, t0); WR_A(1, dA0, t0);
        LD_B(0, 0, t0); WR_B(0, dB0, t0);
        LD_B(1, 0, t0); WR_B(1, dB0, t0);
        LD_A(0, 1, t0); WR_A(0, dA1, t0);
        LD_B(0, 1, t0); WR_B(0, dB1, t0);
        LD_B(1, 1, t0); WR_B(1, dB1, t0);
    }
    LD_A(1, 1, gO);
    LD_A(0, (2 < NT ? 2 : NTm1), gE);
#pragma unroll
    for (int i = 0; i < 8; i++)
#pragma unroll
        for (int j = 0; j < NI; j++) acc[i][j] = f32x4{0.f, 0.f, 0.f, 0.f};
    asm volatile("s_waitcnt lgkmcnt(0)" ::: "memory");
    __builtin_amdgcn_s_barrier();

    const int NW = NT / 2;
    for (int ww = 0; ww < NW; ++ww) {
        const int T = 2 * ww;
        const int kt2 = (T + 2 < NT) ? T + 2 : NTm1;
        const int kt3 = (T + 3 < NT) ? T + 3 : NTm1;
        const int kt4 = (T + 4 < NT) ? T + 4 : NTm1;

        LDA(pa0k0, pa0k1, 0); LDB(pb0k0, pb0k1, 0, b0); LGHINT();
        MIDBAR();
        WR_A(1, dA1, gO); LD_B(0, kt2, gO);          // ph1: write A1(T+1)
        MMQ(0, 0, b0); ENDBAR();
        LDB(pb0k0, pb0k1, 1, b1);
        MIDBAR();
        WR_A(0, dA0, gE); LD_B(1, kt2, gE);          // ph2: write A0(T+2)
        MMQ(0, 1, b1); ENDBAR();
        LDA(pa0k0, pa0k1, 1);
        MIDBAR();
        WR_B(0, dB0, gO); LD_A(1, kt2, gO);          // ph3: write B0(T+2)
        MMQ(1, 1, b1); ENDBAR();
        MIDBAR();
        WR_B(1, dB0, gE); LD_A(0, kt3, gE);          // ph4: write B1(T+2)
        MMQ(1, 0, b0); ENDBAR();
        LDA(pa1k0, pa1k1, 0); LDB(pb1k0, pb1k1, 0, b0); LGHINT();
        MIDBAR();
        WR_A(1, dA0, gO); LD_B(0, kt3, gO);          // ph5: write A1(T+2)
        MMQ(0, 0, b0); ENDBAR();
        LDB(pb1k0, pb1k1, 1, b1);
        MIDBAR();
        WR_A(0, dA1, gE); LD_B(1, kt3, gE);          // ph6: write A0(T+3)
        MMQ(0, 1, b1); ENDBAR();
        LDA(pa1k0, pa1k1, 1);
        MIDBAR();
        WR_B(0, dB1, gO); LD_A(1, kt3, gO);          // ph7: write B0(T+3)
        MMQ(1, 1, b1); ENDBAR();
        MIDBAR();
        WR_B(1, dB1, gE); LD_A(0, kt4, gE);          // ph8: write B1(T+3)
        MMQ(1, 0, b0); ENDBAR();
    }

    const int r0 = m0 + wr * 128 + fq * 4;
    const int c0 = n0 + wc * (BN / 4) + fr;
    unsigned short* C = Cout + (size_t)e * M * N;
#pragma unroll
    for (int mi = 0; mi < 8; mi++)
#pragma unroll
        for (int ni = 0; ni < NI; ni++) {
            int row = r0 + mi * 16, col = c0 + ni * 16;
#pragma unroll
            for (int r = 0; r < 4; r++)
                C[(size_t)(row + r) * N + col] = f2bf(gelu_tanh(acc[mi][ni][r]));
        }
#undef MIDBAR
#undef ENDBAR
#undef LGHINT
}

// ---------- GEMM2: 8-phase, BN=128, 4Mx2N square-per-wave, UNIT-MATCHED ----
// R18's bug: read quadrants didn't match stage units (A-unit0 = rows
// {0-63,128-191}, unit1 = {64-127,192-255}; B-unit nq = rows with bit4==nq).
// Fix: quadrant q reads ONLY unit q. A: wave base (wr&1)*32+(wr>>1)*128,
// q0 = base+{0,16} (unit0), q1 = base+64+{0,16} (unit1). B: base wc*64,
// frag (nq,ni) at base + nq*16 + ni*32 (bit4 = nq). Coverage disjoint+
// complete; stage slots identical to R11 (each unit's last reader drains
// at its phase's lgkm0 before ENDBAR -> stage a phase later is safe).

template <int GX, int GY>
__global__ __launch_bounds__(512, 2)
void gemm2q(const unsigned short* __restrict__ A,
            const unsigned short* __restrict__ B,
            float* __restrict__ Cout, int M, int N, int K) {
    constexpr int BM = 256, BN = 128, BK = 64;
    constexpr int S  = BN / 8;            // 16
    constexpr int ABYTES = BM * BK * 2;   // 32768
    constexpr int BBYTES = BN * BK * 2;   // 16384
    constexpr int BUF = ABYTES + BBYTES;
    constexpr int VMC = 4;
    constexpr int NWG = NE * GX * GY;

    __shared__ __align__(16) char lds[2 * BUF];

    const int lin = blockIdx.x;
    const int wid = (lin & 7) * (NWG >> 3) + (lin >> 3);
    const int e   = wid / (GX * GY);
    const int rem = wid % (GX * GY);
    const int m0  = (rem % GX) * BM;
    const int n0  = (rem / GX) * BN;

    const size_t K2 = (size_t)K * 2;
    const char* Ae = (const char*)(A + (size_t)e * M * K);
    const char* Be = (const char*)(B + (size_t)e * N * K);

    const int tid  = threadIdx.x;
    const int lane = tid & 63;
    const int w    = tid >> 6;
    const int wr   = w >> 1;              // 0..3
    const int wc   = w & 1;               // 0..1
    const int fr   = lane & 15, fq = lane >> 4;

    // ---- staging (identical to gemm8p<128>) ----
    const int rA  = tid >> 3;
    const int kb  = (tid & 7) * 16;
    const int kbs = kb ^ ((rA & 7) << 4);
    const char* aptr = Ae + (size_t)(m0 + rA) * K2 + kbs;
    const int   fB   = (rA / S) * 2 * S + (rA % S);
    const char* bptr = Be + (size_t)(n0 + fB) * K2 + kbs;
    char* dA0 = lds + rA * 128 + kb;
    char* dA1 = dA0 + BUF;
    char* dB0 = lds + ABYTES + fB * 128 + kb;
    char* dB1 = dB0 + BUF;

    auto SA = [&](int au, int kt, char* d) {      // A-unit au: rows rA+au*64, rA+au*64+128
        const char* s = aptr + (size_t)kt * 128;
#pragma unroll
        for (int i = 0; i < 2; i++)
            gload_lds16(s + (size_t)(au * 64 + i * 128) * K2,
                        d + (au * 64 + i * 128) * 128);
    };
    auto SB = [&](int bu, int kt, char* d) {      // B-unit bu: rows fB+bu*16 (bit4==bu)
        const char* s = bptr + (size_t)kt * 128;
        gload_lds16(s + (size_t)(bu * S) * K2, d + (bu * S) * 128);
    };

    // ---- LDS read bases (unit-matched quadrants) ----
    const int kx0   = (fq * 16) ^ ((lane & 7) << 4);
    const int aBase = (wr & 1) * 32 + (wr >> 1) * 128;  // q-mq rows: aBase + mq*64 + mi*16
    const int bBase = wc * 64;                          // frag (nq,ni): bBase + nq*16 + ni*32
    const char* paA = lds + (aBase + fr) * 128;
    const char* paB = lds + ABYTES + (bBase + fr) * 128;
    const char* pa0k0 = paA + kx0;        const char* pa0k1 = paA + (kx0 ^ 64);
    const char* pa1k0 = pa0k0 + BUF;      const char* pa1k1 = pa0k1 + BUF;
    const char* pb0k0 = paB + kx0;        const char* pb0k1 = paB + (kx0 ^ 64);
    const char* pb1k0 = pb0k0 + BUF;      const char* pb1k1 = pb0k1 + BUF;

    f32x4 acc[4][4];
#pragma unroll
    for (int i = 0; i < 4; i++)
#pragma unroll
        for (int j = 0; j < 4; j++) acc[i][j] = f32x4{0.f, 0.f, 0.f, 0.f};

    bf16x8 a[2][2], b0[2][2], b1[2][2];

    auto LDA = [&](const char* p0, const char* p1, int mq) {
#pragma unroll
        for (int mi = 0; mi < 2; mi++) {
            a[mi][0] = *(const bf16x8*)(p0 + mq * 8192 + mi * 2048);
            a[mi][1] = *(const bf16x8*)(p1 + mq * 8192 + mi * 2048);
        }
    };
    auto LDB = [&](const char* p0, const char* p1, int nq, bf16x8 (&bb)[2][2]) {
#pragma unroll
        for (int ni = 0; ni < 2; ni++) {
            bb[ni][0] = *(const bf16x8*)(p0 + (nq * 16 + ni * 32) * 128);
            bb[ni][1] = *(const bf16x8*)(p1 + (nq * 16 + ni * 32) * 128);
        }
    };
    auto MMQ = [&](int mq, int nq, bf16x8 (&bb)[2][2]) {
        __builtin_amdgcn_s_setprio(1);
#pragma unroll
        for (int mi = 0; mi < 2; mi++)
#pragma unroll
            for (int ni = 0; ni < 2; ni++) {
                f32x4& c = acc[mq * 2 + mi][nq * 2 + ni];
                c = __builtin_amdgcn_mfma_f32_16x16x32_bf16(a[mi][0], bb[ni][0], c, 0, 0, 0);
                c = __builtin_amdgcn_mfma_f32_16x16x32_bf16(a[mi][1], bb[ni][1], c, 0, 0, 0);
            }
        __builtin_amdgcn_s_setprio(0);
    };

#define MIDBAR()  __builtin_amdgcn_s_barrier();                                      \
                  asm volatile("s_waitcnt lgkmcnt(0)" ::: "memory")
#define ENDBAR()  __builtin_amdgcn_s_barrier()
#define VMW()     asm volatile("s_waitcnt vmcnt(%0)" :: "n"(VMC) : "memory")

    const int NT   = K / BK;
    const int NTm1 = NT - 1;

    // prologue: tile0 {A0,B0,B1,A1}, tile1 {A0,B0,B1}; drain tile0, keep 4
    SA(0, 0, dA0); SB(0, 0, dB0); SB(1, 0, dB0); SA(1, 0, dA0);
    SA(0, 1, dA1); SB(0, 1, dB1); SB(1, 1, dB1);
    VMW();
    __builtin_amdgcn_s_barrier();

    const int NW = NT / 2;
    for (int ww = 0; ww < NW; ++ww) {
        const int T = 2 * ww;
        const int kt1 = T + 1;
        const int kt2 = (T + 2 < NT) ? T + 2 : NTm1;
        const int kt3 = (T + 3 < NT) ? T + 3 : NTm1;

        // ---- buf0 half: tile T ----
        LDA(pa0k0, pa0k1, 0); LDB(pb0k0, pb0k1, 0, b0); SA(1, kt1, dA1);
        MIDBAR(); MMQ(0, 0, b0); ENDBAR();                       // ph1 (reads unit A0,B0)
        LDB(pb0k0, pb0k1, 1, b1); SA(0, kt2, dA0);
        MIDBAR(); MMQ(0, 1, b1); ENDBAR();                       // ph2 (reads unit B1)
        LDA(pa0k0, pa0k1, 1); SB(0, kt2, dB0);
        MIDBAR(); MMQ(1, 1, b1); ENDBAR();                       // ph3 (reads unit A1)
        SB(1, kt2, dB0);
        MIDBAR(); MMQ(1, 0, b0); VMW(); ENDBAR();                // ph4
        // ---- buf1 half: tile T+1 ----
        LDA(pa1k0, pa1k1, 0); LDB(pb1k0, pb1k1, 0, b0); SA(1, kt2, dA0);
        MIDBAR(); MMQ(0, 0, b0); ENDBAR();                       // ph5
        LDB(pb1k0, pb1k1, 1, b1); SA(0, kt3, dA1);
        MIDBAR(); MMQ(0, 1, b1); ENDBAR();                       // ph6
        LDA(pa1k0, pa1k1, 1); SB(0, kt3, dB1);
        MIDBAR(); MMQ(1, 1, b1); ENDBAR();                       // ph7
        SB(1, kt3, dB1);
        MIDBAR(); MMQ(1, 0, b0); VMW(); ENDBAR();                // ph8
    }
    asm volatile("s_waitcnt vmcnt(0)" ::: "memory");   // drain tail junk stages

    // epilogue: acc[ai][aj]; row = aBase + (ai>>1)*64 + (ai&1)*16;
    //           col = bBase + (aj>>1)*16 + (aj&1)*32
    const int r0 = m0 + aBase + fq * 4;
    const int c0 = n0 + bBase + fr;
    float* C = Cout + (size_t)e * M * N;
#pragma unroll
    for (int ai = 0; ai < 4; ai++)
#pragma unroll
        for (int aj = 0; aj < 4; aj++) {
            int row = r0 + (ai >> 1) * 64 + (ai & 1) * 16;
            int col = c0 + (aj >> 1) * 16 + (aj & 1) * 32;
#pragma unroll
            for (int r = 0; r < 4; r++)
                C[(size_t)(row + r) * N + col] = acc[ai][aj][r];
        }
#undef MIDBAR
#undef ENDBAR
#undef VMW
}

// ---------- fallback: fused fp32, zero workspace (correctness insurance) ----------

__global__ void fused_fallback(const float* __restrict__ x,
                               const float* __restrict__ w1,
                               const float* __restrict__ w2,
                               float* __restrict__ out) {
    __shared__ float xs[HID];
    __shared__ float hs[FFN];
    const int tok = blockIdx.x;
    const int e   = tok / TPE;
    const float* w1e = w1 + (size_t)e * FFN * HID;
    const float* w2e = w2 + (size_t)e * FFN * HID;
    const int t = threadIdx.x;
    for (int i = t; i < HID; i += 256) xs[i] = x[(size_t)tok * HID + i];
    __syncthreads();
    for (int f = t; f < FFN; f += 256) {
        const float* wr_ = w1e + (size_t)f * HID;
        float s = 0.f;
        for (int k = 0; k < HID; k++) s += xs[k] * wr_[k];
        hs[f] = gelu_tanh(s);
    }
    __syncthreads();
    for (int h = t; h < HID; h += 256) {
        float s = 0.f;
        for (int f = 0; f < FFN; f++) s += hs[f] * w2e[(size_t)f * HID + h];
        out[(size_t)tok * HID + h] = s;
    }
}

// ---------- launch ----------

extern "C" void kernel_launch(void* const* d_in, const int* in_sizes, int n_in,
                              void* d_out, int out_size, void* d_ws, size_t ws_size,
                              hipStream_t stream) {
    const float* x  = (const float*)d_in[0];
    const float* w1 = (const float*)d_in[1];
    const float* w2 = (const float*)d_in[2];
    float* out = (float*)d_out;

    const size_t W2B = (size_t)NE * FFN * HID * 2;   // 64 MB  bf16 w2t
    const size_t HB  = (size_t)TOK * FFN * 2;        // 64 MB  bf16 h
    const size_t need = W2B + HB;                    // 128 MB

    if (ws_size >= need) {
        char* ws = (char*)d_ws;
        unsigned short* w2t = (unsigned short*)ws;
        unsigned short* hb  = (unsigned short*)(ws + W2B);

        // prep: only w2 transpose-convert (192 MB traffic)
        transpose_cvt<<<dim3(FFN / 64, HID / 64, NE), 256, 0, stream>>>(w2, w2t);

        // GEMM1 fused-cvt: h = gelu(x @ w1^T), f32 inputs -> 512 blocks
        gemm8f<TPE / 256, FFN / 256><<<NE * (TPE / 256) * (FFN / 256), 512, 0, stream>>>(
            x, w1, hb, TPE, FFN, HID);
        // GEMM2: out = h @ w2t^T -> 256 blocks, unit-matched 4Mx2N split
        gemm2q<TPE / 256, HID / 128><<<NE * (TPE / 256) * (HID / 128), 512, 0, stream>>>(
            hb, w2t, out, TPE, HID, FFN);
    } else {
        fused_fallback<<<TOK, 256, 0, stream>>>(x, w1, w2, out);
    }
}